// Round 4
// baseline (17373.973 us; speedup 1.0000x reference)
//
#include <hip/hip_runtime.h>
#include <hip/hip_bf16.h>
#include <cstdint>

#define T_STEPS 512
#define BATCH   64
#define XDIM    64
#define HDIM    1024
#define YDIM    64

typedef unsigned short ushort_t;
typedef uint32_t u32;
typedef __attribute__((ext_vector_type(8))) short short8;
typedef __attribute__((ext_vector_type(4))) float f32x4;

// ---------- helpers ----------
__device__ __forceinline__ void unpack8(const uint4 v, float* f) {
  f[0] = __uint_as_float(v.x << 16);
  f[1] = __uint_as_float(v.x & 0xffff0000u);
  f[2] = __uint_as_float(v.y << 16);
  f[3] = __uint_as_float(v.y & 0xffff0000u);
  f[4] = __uint_as_float(v.z << 16);
  f[5] = __uint_as_float(v.z & 0xffff0000u);
  f[6] = __uint_as_float(v.w << 16);
  f[7] = __uint_as_float(v.w & 0xffff0000u);
}

__device__ __forceinline__ ushort_t f2bf(float x) {
  u32 u = __float_as_uint(x);
  u32 r = (u + 0x7fffu + ((u >> 16) & 1u)) >> 16;  // round-nearest-even
  return (ushort_t)r;
}

__device__ __forceinline__ float sigm(float x) { return 1.0f / (1.0f + expf(-x)); }

__device__ __forceinline__ void dot4(float& acc, const float* a, const float4 w) {
  acc = fmaf(a[0], w.x, acc);
  acc = fmaf(a[1], w.y, acc);
  acc = fmaf(a[2], w.z, acc);
  acc = fmaf(a[3], w.w, acc);
}

// ---------- encoder ----------
__global__ __launch_bounds__(256) void enc_kernel(
    const float* __restrict__ x, const float* __restrict__ enc_w,
    const float* __restrict__ enc_b, ushort_t* __restrict__ enc_out)
{
  const int lane = threadIdx.x & 63;
  const int wv   = threadIdx.x >> 6;
  const int cb = blockIdx.x & 15;
  const int rb = blockIdx.x >> 4;
  const int j  = cb * 64 + lane;
  const int r0 = rb * 16 + wv * 4;
  const float* wrow = enc_w + (size_t)j * XDIM;
  const float* xr   = x + (size_t)r0 * XDIM;
  float acc[4] = {0.f, 0.f, 0.f, 0.f};
#pragma unroll
  for (int k = 0; k < XDIM; k += 4) {
    float4 w4 = *(const float4*)(wrow + k);
#pragma unroll
    for (int rr = 0; rr < 4; ++rr) {
      float4 xv = *(const float4*)(xr + rr * XDIM + k);
      acc[rr] = fmaf(xv.x, w4.x, acc[rr]);
      acc[rr] = fmaf(xv.y, w4.y, acc[rr]);
      acc[rr] = fmaf(xv.z, w4.z, acc[rr]);
      acc[rr] = fmaf(xv.w, w4.w, acc[rr]);
    }
  }
  float b = enc_b[j];
#pragma unroll
  for (int rr = 0; rr < 4; ++rr)
    enc_out[(size_t)(r0 + rr) * HDIM + j] = f2bf(tanhf(acc[rr] + b));
}

// ---------- weight fragment pre-pack (chunk c = bid*128 + g*64 + kh*32 + tl*16 + ko) ----------
__global__ __launch_bounds__(256) void wprep_kernel(
    const float* __restrict__ w_ih, const float* __restrict__ w_hh,
    ushort_t* __restrict__ wfrag)
{
  const int lane = threadIdx.x & 63;
  const int wv   = threadIdx.x >> 6;
  const int c    = blockIdx.x * 4 + wv;
  const int ko = c & 15;
  const int tl = (c >> 4) & 1;
  const int kh = (c >> 5) & 1;
  const int g  = (c >> 6) & 1;
  const int bid = c >> 7;
  const int layer = bid >> 7;
  const int j0 = (bid & 127) * 8;
  const int col = lane & 15, kgrp = lane >> 4;
  const int k = kh * 512 + ko * 32 + kgrp * 8;

  short8 v;
  const bool zero = (tl == 1) && (col >= 8);
  if (!zero) {
    int row;
    if (tl == 0) row = (col < 8) ? (j0 + col) : (HDIM + j0 + col - 8);
    else         row = 2 * HDIM + j0 + col;
    const float* src = (g ? w_hh : w_ih) + (size_t)layer * 3 * HDIM * HDIM
                     + (size_t)row * HDIM + k;
#pragma unroll
    for (int e = 0; e < 8; ++e) v[e] = (short)f2bf(src[e]);
  } else {
#pragma unroll
    for (int e = 0; e < 8; ++e) v[e] = 0;
  }
  *(short8*)(wfrag + (size_t)c * 512 + lane * 8) = v;
}

// ---------- lean grid barrier: 1 release-add + relaxed spin + 1 acquire per block ----------
__device__ __forceinline__ void gbar(u32* cnt, int phase) {
  __syncthreads();  // drains each wave's vmem ops; block-wide order
  if (threadIdx.x == 0) {
    u32* p = cnt + phase;
    __hip_atomic_fetch_add(p, 1u, __ATOMIC_RELEASE, __HIP_MEMORY_SCOPE_AGENT);
    while (__hip_atomic_load(p, __ATOMIC_RELAXED, __HIP_MEMORY_SCOPE_AGENT) < 256u)
      __builtin_amdgcn_s_sleep(1);
    (void)__hip_atomic_load(p, __ATOMIC_ACQUIRE, __HIP_MEMORY_SCOPE_AGENT);
  }
  __syncthreads();
}

// ---------- persistent recurrent kernel ----------
// 256 blocks x 512 threads, 1 block/CU. Block bid: layer=bid>>7, owns h-cols j0=(bid&127)*8.
// Wave: mp=wid&1 (m-pair), g=(wid>>1)&1 (ih/hh), kh=wid>>2 (K half).
// Weights live in VGPRs for all phases; one lean barrier per phase.
__global__ __launch_bounds__(512, 1) void rnn_persist(
    const ushort_t* __restrict__ ench1,   // enc slices; slice t overwritten by h1(t)
    const ushort_t* __restrict__ wfrag,
    const float* __restrict__ b_ih, const float* __restrict__ b_hh,
    ushort_t* __restrict__ h0s, ushort_t* __restrict__ h1s,
    float* __restrict__ h0f, float* __restrict__ h1f,
    ushort_t* __restrict__ h1_all,        // == ench1
    u32* __restrict__ cnt)
{
  __shared__ float lds_part[32 * 256];

  const int tid  = threadIdx.x;
  const int lane = tid & 63;
  const int wid  = tid >> 6;
  const int bid  = blockIdx.x;
  const int layer = bid >> 7;
  const int j0    = (bid & 127) * 8;
  const int mp = wid & 1, g = (wid >> 1) & 1, kh = wid >> 2;
  const int col = lane & 15, kgrp = lane >> 4;
  const bool isL1 = (layer == 1);

  // ---- one-time: B fragments -> registers (coalesced 16B/lane) ----
  const ushort_t* wb = wfrag + ((size_t)bid * 128 + (size_t)g * 64 + (size_t)kh * 32) * 512;
  short8 bfr[2][16];
#pragma unroll
  for (int tl = 0; tl < 2; ++tl)
#pragma unroll
    for (int ko = 0; ko < 16; ++ko)
      bfr[tl][ko] = *(const short8*)(wb + (size_t)(tl * 16 + ko) * 512 + lane * 8);

  // ---- one-time: biases ----
  float bA = 0.f, bB = 0.f, bC = 0.f;
  {
    const float* bi = b_ih + layer * 3 * HDIM;
    const float* bh = b_hh + layer * 3 * HDIM;
    if (col < 8) {
      const int j = j0 + col;
      bA = bi[j] + bh[j];
      bB = bi[2 * HDIM + j];
      bC = bh[2 * HDIM + j];
    } else {
      const int j = j0 + col - 8;
      bA = bi[HDIM + j] + bh[HDIM + j];
    }
  }

  for (int s = 0; s <= T_STEPS; ++s) {
    const bool active = isL1 ? (s >= 1) : (s < T_STEPS);
    if (active) {
      const int t = isL1 ? (s - 1) : s;
      const ushort_t* A1 = isL1 ? (h0s + ((s + 1) & 1) * (BATCH * HDIM))
                                : (ench1 + (size_t)t * (BATCH * HDIM));
      const ushort_t* A2 = isL1 ? (h1s + (s & 1) * (BATCH * HDIM))
                                : (h0s + ((s + 1) & 1) * (BATCH * HDIM));
      const ushort_t* A = g ? A2 : A1;

      f32x4 acc00 = {0,0,0,0}, acc01 = {0,0,0,0}, acc10 = {0,0,0,0}, acc11 = {0,0,0,0};
      const ushort_t* Arow0 = A + (size_t)(mp * 32 + col) * HDIM + kh * 512 + kgrp * 8;
      const ushort_t* Arow1 = Arow0 + 16 * HDIM;
#pragma unroll
      for (int ko = 0; ko < 16; ++ko) {
        const short8 a0 = *(const short8*)(Arow0 + ko * 32);
        const short8 a1 = *(const short8*)(Arow1 + ko * 32);
        acc00 = __builtin_amdgcn_mfma_f32_16x16x32_bf16(a0, bfr[0][ko], acc00, 0, 0, 0);
        acc01 = __builtin_amdgcn_mfma_f32_16x16x32_bf16(a0, bfr[1][ko], acc01, 0, 0, 0);
        acc10 = __builtin_amdgcn_mfma_f32_16x16x32_bf16(a1, bfr[0][ko], acc10, 0, 0, 0);
        acc11 = __builtin_amdgcn_mfma_f32_16x16x32_bf16(a1, bfr[1][ko], acc11, 0, 0, 0);
      }
      const int base = (wid * 4) * 256 + lane * 4;
      *(f32x4*)&lds_part[base      ] = acc00;
      *(f32x4*)&lds_part[base + 256] = acc01;
      *(f32x4*)&lds_part[base + 512] = acc10;
      *(f32x4*)&lds_part[base + 768] = acc11;
    }
    __syncthreads();

    if (active && wid < 4) {
      const int m = wid, mpe = m >> 1, ime = m & 1;
      const int i00 = ((0 * 4 + 0 * 2 + mpe) * 4 + ime * 2);
      const int i01 = ((1 * 4 + 0 * 2 + mpe) * 4 + ime * 2);
      const int i10 = ((0 * 4 + 1 * 2 + mpe) * 4 + ime * 2);
      const int i11 = ((1 * 4 + 1 * 2 + mpe) * 4 + ime * 2);
      const int lo = lane * 4;
      f32x4 girz = *(f32x4*)&lds_part[i00 * 256 + lo] + *(f32x4*)&lds_part[i01 * 256 + lo];
      f32x4 gin  = *(f32x4*)&lds_part[(i00 + 1) * 256 + lo] + *(f32x4*)&lds_part[(i01 + 1) * 256 + lo];
      f32x4 ghrz = *(f32x4*)&lds_part[i10 * 256 + lo] + *(f32x4*)&lds_part[i11 * 256 + lo];
      f32x4 ghn  = *(f32x4*)&lds_part[(i10 + 1) * 256 + lo] + *(f32x4*)&lds_part[(i11 + 1) * 256 + lo];

      const int s1 = (s + 1) & 1, s0 = s & 1;
      const float* hpf = isL1 ? (h1f + s0 * (BATCH * HDIM)) : (h0f + s1 * (BATCH * HDIM));
      float* hfd       = isL1 ? (h1f + s1 * (BATCH * HDIM)) : (h0f + s0 * (BATCH * HDIM));
      ushort_t* hdst   = isL1 ? (h1s + s1 * (BATCH * HDIM)) : (h0s + s0 * (BATCH * HDIM));
      ushort_t* hall   = isL1 ? (h1_all + (size_t)(s - 1) * (BATCH * HDIM)) : (ushort_t*)0;

#pragma unroll
      for (int e = 0; e < 4; ++e) {
        const float rz = sigm(girz[e] + ghrz[e] + bA);
        const float nv = tanhf(gin[e] + bB + rz * (ghn[e] + bC));
        const float zv = __shfl_xor(rz, 8);
        if (col < 8) {
          const int b = m * 16 + kgrp * 4 + e;
          const float hpv = hpf[b * HDIM + j0 + col];
          const float h = (1.f - zv) * nv + zv * hpv;
          hfd[b * HDIM + j0 + col] = h;
          const ushort_t hb = f2bf(h);
          hdst[b * HDIM + j0 + col] = hb;
          if (hall) hall[b * HDIM + j0 + col] = hb;
        }
      }
    }
    gbar(cnt, s);
  }
}

// ---------- decoder ----------
__global__ __launch_bounds__(256) void dec_kernel(
    const ushort_t* __restrict__ h1_all, const float* __restrict__ dec_w,
    const float* __restrict__ dec_b, ushort_t* __restrict__ rnn_out)
{
  const int lane = threadIdx.x & 63;
  const int wv   = threadIdx.x >> 6;
  const int cb = blockIdx.x & 15;
  const int rb = blockIdx.x >> 4;
  const int row = rb * 64 + lane;
  const int j0  = cb * 64 + wv * 16;
  const ushort_t* a = h1_all + (size_t)row * HDIM;
  float acc[16];
#pragma unroll
  for (int c = 0; c < 16; ++c) acc[c] = 0.f;

#pragma unroll 1
  for (int k = 0; k < HDIM; k += 8) {
    float af[8];
    uint4 v = *(const uint4*)(a + k);
    unpack8(v, af);
#pragma unroll
    for (int c = 0; c < 16; ++c) {
      const float* wr = dec_w + (size_t)(j0 + c) * HDIM + k;
      dot4(acc[c], af,     *(const float4*)wr);
      dot4(acc[c], af + 4, *(const float4*)(wr + 4));
    }
  }
#pragma unroll
  for (int c = 0; c < 16; ++c) {
    float vq = tanhf(acc[c] + dec_b[j0 + c]);
    rnn_out[(size_t)row * HDIM + j0 + c] = f2bf(vq);
  }
}

// ---------- heads ----------
__global__ __launch_bounds__(256) void head_kernel(
    const ushort_t* __restrict__ rnn_out,
    const float* __restrict__ exp_w, const float* __restrict__ exp_b,
    const float* __restrict__ log_w, const float* __restrict__ log_b,
    float* __restrict__ outm, float* __restrict__ outv)
{
  const int lane = threadIdx.x & 63;
  const int wv   = threadIdx.x >> 6;
  const int row = blockIdx.x * 64 + lane;
  const int c0  = wv * 32;
  const ushort_t* a = rnn_out + (size_t)row * HDIM;
  const float* wmat = (c0 < 64) ? exp_w : log_w;
  const int cc0 = c0 & 63;

  float acc[32];
#pragma unroll
  for (int i = 0; i < 32; ++i) acc[i] = 0.f;

#pragma unroll 1
  for (int k = 0; k < HDIM; k += 8) {
    float af[8];
    uint4 v = *(const uint4*)(a + k);
    unpack8(v, af);
#pragma unroll
    for (int i = 0; i < 32; ++i) {
      const float* wr = wmat + (size_t)(cc0 + i) * HDIM + k;
      dot4(acc[i], af,     *(const float4*)wr);
      dot4(acc[i], af + 4, *(const float4*)(wr + 4));
    }
  }

  if (c0 < 64) {
#pragma unroll
    for (int i = 0; i < 32; ++i) {
      int y = cc0 + i;
      outm[(size_t)row * YDIM + y] = acc[i] + exp_b[y];
    }
  } else {
#pragma unroll
    for (int i = 0; i < 32; ++i) {
      int y = cc0 + i;
      outv[(size_t)row * YDIM + y] = expf(acc[i] + log_b[y]);
    }
  }
}

// ---------- host ----------
extern "C" void kernel_launch(void* const* d_in, const int* in_sizes, int n_in,
                              void* d_out, int out_size, void* d_ws, size_t ws_size,
                              hipStream_t stream) {
  (void)in_sizes; (void)n_in; (void)out_size; (void)ws_size;
  const float* x     = (const float*)d_in[0];
  const float* enc_w = (const float*)d_in[1];
  const float* enc_b = (const float*)d_in[2];
  const float* w_ih  = (const float*)d_in[3];
  const float* w_hh  = (const float*)d_in[4];
  const float* b_ih  = (const float*)d_in[5];
  const float* b_hh  = (const float*)d_in[6];
  const float* dec_w = (const float*)d_in[7];
  const float* dec_b = (const float*)d_in[8];
  const float* exp_w = (const float*)d_in[9];
  const float* exp_b = (const float*)d_in[10];
  const float* log_w = (const float*)d_in[11];
  const float* log_b = (const float*)d_in[12];
  float* out = (float*)d_out;

  char* ws = (char*)d_ws;
  ushort_t* h0s   = (ushort_t*)ws;                        // 256 KB
  ushort_t* h1s   = (ushort_t*)(ws + 262144);             // 256 KB
  float*    h0f   = (float*)(ws + 524288);                // 512 KB
  float*    h1f   = (float*)(ws + 1048576);               // 512 KB
  u32*      cnt   = (u32*)(ws + 1572864);                 // 513 u32 barrier counters
  ushort_t* wfrag = (ushort_t*)(ws + 2097152);            // 32 MB (reused as rnn_out staging)
  ushort_t* ench1 = (ushort_t*)(ws + 2097152 + 33554432); // 64 MB enc slices / h1_all

  hipMemsetAsync(ws, 0, 1576960, stream);  // h-state buffers + barrier counters

  enc_kernel<<<32768, 256, 0, stream>>>(x, enc_w, enc_b, ench1);
  wprep_kernel<<<8192, 256, 0, stream>>>(w_ih, w_hh, wfrag);

  {
    void* args[10];
    args[0] = (void*)&ench1;
    args[1] = (void*)&wfrag;
    args[2] = (void*)&b_ih;
    args[3] = (void*)&b_hh;
    args[4] = (void*)&h0s;
    args[5] = (void*)&h1s;
    args[6] = (void*)&h0f;
    args[7] = (void*)&h1f;
    args[8] = (void*)&ench1;
    args[9] = (void*)&cnt;
    hipLaunchCooperativeKernel((const void*)rnn_persist, dim3(256), dim3(512),
                               args, 0, stream);
  }

  ushort_t* staging = wfrag;
  for (int half = 0; half < 2; ++half) {
    const ushort_t* h1p = ench1 + (size_t)half * 16384 * HDIM;
    dec_kernel<<<4096, 256, 0, stream>>>(h1p, dec_w, dec_b, staging);
    float* outm = out + (size_t)half * 16384 * YDIM;
    float* outv = out + (size_t)T_STEPS * BATCH * YDIM + (size_t)half * 16384 * YDIM;
    head_kernel<<<256, 256, 0, stream>>>(staging, exp_w, exp_b, log_w, log_b, outm, outv);
  }
}

// Round 5
// 17191.182 us; speedup vs baseline: 1.0106x; 1.0106x over previous
//
#include <hip/hip_runtime.h>
#include <hip/hip_bf16.h>
#include <cstdint>

#define T_STEPS 512
#define BATCH   64
#define XDIM    64
#define HDIM    1024
#define YDIM    64

typedef unsigned short ushort_t;
typedef uint32_t u32;
typedef unsigned long long u64;
typedef __attribute__((ext_vector_type(8))) short short8;
typedef __attribute__((ext_vector_type(4))) float f32x4;

// ---------- helpers ----------
__device__ __forceinline__ void unpack8(const uint4 v, float* f) {
  f[0] = __uint_as_float(v.x << 16);
  f[1] = __uint_as_float(v.x & 0xffff0000u);
  f[2] = __uint_as_float(v.y << 16);
  f[3] = __uint_as_float(v.y & 0xffff0000u);
  f[4] = __uint_as_float(v.z << 16);
  f[5] = __uint_as_float(v.z & 0xffff0000u);
  f[6] = __uint_as_float(v.w << 16);
  f[7] = __uint_as_float(v.w & 0xffff0000u);
}

__device__ __forceinline__ u32 f2bf_u(float x) {
  u32 u = __float_as_uint(x);
  return (u + 0x7fffu + ((u >> 16) & 1u)) >> 16;  // round-nearest-even
}
__device__ __forceinline__ ushort_t f2bf(float x) { return (ushort_t)f2bf_u(x); }

__device__ __forceinline__ float sigm(float x) { return 1.0f / (1.0f + expf(-x)); }

__device__ __forceinline__ void dot4(float& acc, const float* a, const float4 w) {
  acc = fmaf(a[0], w.x, acc);
  acc = fmaf(a[1], w.y, acc);
  acc = fmaf(a[2], w.z, acc);
  acc = fmaf(a[3], w.w, acc);
}

// ---------- coherence-point (sc1) access helpers: no cache maintenance ----------
__device__ __forceinline__ u64 ld_sc64(const ushort_t* p) {
  return __hip_atomic_load((u64*)p, __ATOMIC_RELAXED, __HIP_MEMORY_SCOPE_AGENT);
}
__device__ __forceinline__ float ld_scf(const float* p) {
  return __hip_atomic_load((float*)p, __ATOMIC_RELAXED, __HIP_MEMORY_SCOPE_AGENT);
}
__device__ __forceinline__ void st_sc32(u32* p, u32 v) {
  __hip_atomic_store(p, v, __ATOMIC_RELAXED, __HIP_MEMORY_SCOPE_AGENT);
}
__device__ __forceinline__ void st_scf(float* p, float v) {
  __hip_atomic_store(p, v, __ATOMIC_RELAXED, __HIP_MEMORY_SCOPE_AGENT);
}
__device__ __forceinline__ short8 ldA_sc(const ushort_t* p) {
  union { short8 s; u64 q[2]; } u;
  u.q[0] = ld_sc64(p);
  u.q[1] = ld_sc64(p + 4);
  return u.s;
}

// ---------- encoder ----------
__global__ __launch_bounds__(256) void enc_kernel(
    const float* __restrict__ x, const float* __restrict__ enc_w,
    const float* __restrict__ enc_b, ushort_t* __restrict__ enc_out)
{
  const int lane = threadIdx.x & 63;
  const int wv   = threadIdx.x >> 6;
  const int cb = blockIdx.x & 15;
  const int rb = blockIdx.x >> 4;
  const int j  = cb * 64 + lane;
  const int r0 = rb * 16 + wv * 4;
  const float* wrow = enc_w + (size_t)j * XDIM;
  const float* xr   = x + (size_t)r0 * XDIM;
  float acc[4] = {0.f, 0.f, 0.f, 0.f};
#pragma unroll
  for (int k = 0; k < XDIM; k += 4) {
    float4 w4 = *(const float4*)(wrow + k);
#pragma unroll
    for (int rr = 0; rr < 4; ++rr) {
      float4 xv = *(const float4*)(xr + rr * XDIM + k);
      acc[rr] = fmaf(xv.x, w4.x, acc[rr]);
      acc[rr] = fmaf(xv.y, w4.y, acc[rr]);
      acc[rr] = fmaf(xv.z, w4.z, acc[rr]);
      acc[rr] = fmaf(xv.w, w4.w, acc[rr]);
    }
  }
  float b = enc_b[j];
#pragma unroll
  for (int rr = 0; rr < 4; ++rr)
    enc_out[(size_t)(r0 + rr) * HDIM + j] = f2bf(tanhf(acc[rr] + b));
}

// ---------- weight fragment pre-pack (chunk c = bid*128 + g*64 + kh*32 + tl*16 + ko) ----------
__global__ __launch_bounds__(256) void wprep_kernel(
    const float* __restrict__ w_ih, const float* __restrict__ w_hh,
    ushort_t* __restrict__ wfrag)
{
  const int lane = threadIdx.x & 63;
  const int wv   = threadIdx.x >> 6;
  const int c    = blockIdx.x * 4 + wv;
  const int ko = c & 15;
  const int tl = (c >> 4) & 1;
  const int kh = (c >> 5) & 1;
  const int g  = (c >> 6) & 1;
  const int bid = c >> 7;
  const int layer = bid >> 7;
  const int j0 = (bid & 127) * 8;
  const int col = lane & 15, kgrp = lane >> 4;
  const int k = kh * 512 + ko * 32 + kgrp * 8;

  short8 v;
  const bool zero = (tl == 1) && (col >= 8);
  if (!zero) {
    int row;
    if (tl == 0) row = (col < 8) ? (j0 + col) : (HDIM + j0 + col - 8);
    else         row = 2 * HDIM + j0 + col;
    const float* src = (g ? w_hh : w_ih) + (size_t)layer * 3 * HDIM * HDIM
                     + (size_t)row * HDIM + k;
#pragma unroll
    for (int e = 0; e < 8; ++e) v[e] = (short)f2bf(src[e]);
  } else {
#pragma unroll
    for (int e = 0; e < 8; ++e) v[e] = 0;
  }
  *(short8*)(wfrag + (size_t)c * 512 + lane * 8) = v;
}

// ---------- fence-free grid barrier: relaxed add + relaxed spin ----------
// Ordering: __syncthreads drains each wave's vmem (sc1 stores are at the
// coherence point once vmcnt==0), so the leader's relaxed atomic arrives after
// all block data is globally visible. Readers use sc1 loads (no stale caches).
__device__ __forceinline__ void gbar(u32* cnt, int phase) {
  __syncthreads();
  if (threadIdx.x == 0) {
    u32* p = cnt + phase;
    __hip_atomic_fetch_add(p, 1u, __ATOMIC_RELAXED, __HIP_MEMORY_SCOPE_AGENT);
    while (__hip_atomic_load(p, __ATOMIC_RELAXED, __HIP_MEMORY_SCOPE_AGENT) < 256u)
      __builtin_amdgcn_s_sleep(2);
  }
  __syncthreads();
}

// ---------- persistent recurrent kernel ----------
// 256 blocks x 512 threads, 1 block/CU. Block bid: layer=bid>>7, owns h-cols j0=(bid&127)*8.
// Wave: mp=wid&1 (m-pair), g=(wid>>1)&1 (ih/hh), kh=wid>>2 (K half).
__global__ __launch_bounds__(512, 1) void rnn_persist(
    const ushort_t* __restrict__ ench1,   // enc slices; slice t overwritten by h1(t)
    const ushort_t* __restrict__ wfrag,
    const float* __restrict__ b_ih, const float* __restrict__ b_hh,
    ushort_t* __restrict__ h0s, ushort_t* __restrict__ h1s,
    float* __restrict__ h0f, float* __restrict__ h1f,
    ushort_t* __restrict__ h1_all,        // == ench1
    u32* __restrict__ cnt)
{
  __shared__ float lds_part[32 * 256];

  const int tid  = threadIdx.x;
  const int lane = tid & 63;
  const int wid  = tid >> 6;
  const int bid  = blockIdx.x;
  const int layer = bid >> 7;
  const int j0    = (bid & 127) * 8;
  const int mp = wid & 1, g = (wid >> 1) & 1, kh = wid >> 2;
  const int col = lane & 15, kgrp = lane >> 4;
  const bool isL1 = (layer == 1);

  // ---- B fragments (plain cached loads; L2 stays hot — no invalidation ever) ----
  const ushort_t* wb = wfrag + ((size_t)bid * 128 + (size_t)g * 64 + (size_t)kh * 32) * 512;
  short8 bfr[2][16];
#pragma unroll
  for (int tl = 0; tl < 2; ++tl)
#pragma unroll
    for (int ko = 0; ko < 16; ++ko)
      bfr[tl][ko] = *(const short8*)(wb + (size_t)(tl * 16 + ko) * 512 + lane * 8);

  // ---- biases ----
  float bA = 0.f, bB = 0.f, bC = 0.f;
  {
    const float* bi = b_ih + layer * 3 * HDIM;
    const float* bh = b_hh + layer * 3 * HDIM;
    if (col < 8) {
      const int j = j0 + col;
      bA = bi[j] + bh[j];
      bB = bi[2 * HDIM + j];
      bC = bh[2 * HDIM + j];
    } else {
      const int j = j0 + col - 8;
      bA = bi[HDIM + j] + bh[HDIM + j];
    }
  }

  for (int s = 0; s <= T_STEPS; ++s) {
    const bool active = isL1 ? (s >= 1) : (s < T_STEPS);
    if (active) {
      const int t = isL1 ? (s - 1) : s;
      const ushort_t* A1 = isL1 ? (h0s + ((s + 1) & 1) * (BATCH * HDIM))
                                : (ench1 + (size_t)t * (BATCH * HDIM));
      const ushort_t* A2 = isL1 ? (h1s + (s & 1) * (BATCH * HDIM))
                                : (h0s + ((s + 1) & 1) * (BATCH * HDIM));
      const ushort_t* A = g ? A2 : A1;
      // enc slices (L0, g=0) are plain-cacheable; all h-state needs sc1 loads
      const bool coh = !(layer == 0 && g == 0);

      f32x4 acc00 = {0,0,0,0}, acc01 = {0,0,0,0}, acc10 = {0,0,0,0}, acc11 = {0,0,0,0};
      const ushort_t* Arow0 = A + (size_t)(mp * 32 + col) * HDIM + kh * 512 + kgrp * 8;
      const ushort_t* Arow1 = Arow0 + 16 * HDIM;
      if (coh) {
#pragma unroll
        for (int ko = 0; ko < 16; ++ko) {
          const short8 a0 = ldA_sc(Arow0 + ko * 32);
          const short8 a1 = ldA_sc(Arow1 + ko * 32);
          acc00 = __builtin_amdgcn_mfma_f32_16x16x32_bf16(a0, bfr[0][ko], acc00, 0, 0, 0);
          acc01 = __builtin_amdgcn_mfma_f32_16x16x32_bf16(a0, bfr[1][ko], acc01, 0, 0, 0);
          acc10 = __builtin_amdgcn_mfma_f32_16x16x32_bf16(a1, bfr[0][ko], acc10, 0, 0, 0);
          acc11 = __builtin_amdgcn_mfma_f32_16x16x32_bf16(a1, bfr[1][ko], acc11, 0, 0, 0);
        }
      } else {
#pragma unroll
        for (int ko = 0; ko < 16; ++ko) {
          const short8 a0 = *(const short8*)(Arow0 + ko * 32);
          const short8 a1 = *(const short8*)(Arow1 + ko * 32);
          acc00 = __builtin_amdgcn_mfma_f32_16x16x32_bf16(a0, bfr[0][ko], acc00, 0, 0, 0);
          acc01 = __builtin_amdgcn_mfma_f32_16x16x32_bf16(a0, bfr[1][ko], acc01, 0, 0, 0);
          acc10 = __builtin_amdgcn_mfma_f32_16x16x32_bf16(a1, bfr[0][ko], acc10, 0, 0, 0);
          acc11 = __builtin_amdgcn_mfma_f32_16x16x32_bf16(a1, bfr[1][ko], acc11, 0, 0, 0);
        }
      }
      const int base = (wid * 4) * 256 + lane * 4;
      *(f32x4*)&lds_part[base      ] = acc00;
      *(f32x4*)&lds_part[base + 256] = acc01;
      *(f32x4*)&lds_part[base + 512] = acc10;
      *(f32x4*)&lds_part[base + 768] = acc11;
    }
    __syncthreads();

    if (active && wid < 4) {
      const int m = wid, mpe = m >> 1, ime = m & 1;
      const int i00 = ((0 * 4 + 0 * 2 + mpe) * 4 + ime * 2);
      const int i01 = ((1 * 4 + 0 * 2 + mpe) * 4 + ime * 2);
      const int i10 = ((0 * 4 + 1 * 2 + mpe) * 4 + ime * 2);
      const int i11 = ((1 * 4 + 1 * 2 + mpe) * 4 + ime * 2);
      const int lo = lane * 4;
      f32x4 girz = *(f32x4*)&lds_part[i00 * 256 + lo] + *(f32x4*)&lds_part[i01 * 256 + lo];
      f32x4 gin  = *(f32x4*)&lds_part[(i00 + 1) * 256 + lo] + *(f32x4*)&lds_part[(i01 + 1) * 256 + lo];
      f32x4 ghrz = *(f32x4*)&lds_part[i10 * 256 + lo] + *(f32x4*)&lds_part[i11 * 256 + lo];
      f32x4 ghn  = *(f32x4*)&lds_part[(i10 + 1) * 256 + lo] + *(f32x4*)&lds_part[(i11 + 1) * 256 + lo];

      const int s1 = (s + 1) & 1, s0 = s & 1;
      const float* hpf = isL1 ? (h1f + s0 * (BATCH * HDIM)) : (h0f + s1 * (BATCH * HDIM));
      float* hfd       = isL1 ? (h1f + s1 * (BATCH * HDIM)) : (h0f + s0 * (BATCH * HDIM));
      ushort_t* hdst   = isL1 ? (h1s + s1 * (BATCH * HDIM)) : (h0s + s0 * (BATCH * HDIM));
      ushort_t* hall   = isL1 ? (h1_all + (size_t)(s - 1) * (BATCH * HDIM)) : (ushort_t*)0;

#pragma unroll
      for (int e = 0; e < 4; ++e) {
        const float rz = sigm(girz[e] + ghrz[e] + bA);
        const float nv = tanhf(gin[e] + bB + rz * (ghn[e] + bC));
        const float zv = __shfl_xor(rz, 8);
        const int b = m * 16 + kgrp * 4 + e;
        float h = 0.f;
        if (col < 8) {
          const float hpv = ld_scf(hpf + b * HDIM + j0 + col);
          h = (1.f - zv) * nv + zv * hpv;
          st_scf(hfd + b * HDIM + j0 + col, h);
        }
        // pack two bf16 (adjacent cols in lane pairs) into one u32 sc1 store
        const u32 hb = f2bf_u(h);
        const u32 pb = (u32)__shfl_xor((int)hb, 1);
        if (col < 8 && (col & 1) == 0) {
          const u32 pack = hb | (pb << 16);
          st_sc32((u32*)(hdst + b * HDIM + j0 + col), pack);
          if (hall) st_sc32((u32*)(hall + b * HDIM + j0 + col), pack);
        }
      }
    }
    if (s < T_STEPS) gbar(cnt, s);
  }
}

// ---------- decoder ----------
__global__ __launch_bounds__(256) void dec_kernel(
    const ushort_t* __restrict__ h1_all, const float* __restrict__ dec_w,
    const float* __restrict__ dec_b, ushort_t* __restrict__ rnn_out)
{
  const int lane = threadIdx.x & 63;
  const int wv   = threadIdx.x >> 6;
  const int cb = blockIdx.x & 15;
  const int rb = blockIdx.x >> 4;
  const int row = rb * 64 + lane;
  const int j0  = cb * 64 + wv * 16;
  const ushort_t* a = h1_all + (size_t)row * HDIM;
  float acc[16];
#pragma unroll
  for (int c = 0; c < 16; ++c) acc[c] = 0.f;

#pragma unroll 1
  for (int k = 0; k < HDIM; k += 8) {
    float af[8];
    uint4 v = *(const uint4*)(a + k);
    unpack8(v, af);
#pragma unroll
    for (int c = 0; c < 16; ++c) {
      const float* wr = dec_w + (size_t)(j0 + c) * HDIM + k;
      dot4(acc[c], af,     *(const float4*)wr);
      dot4(acc[c], af + 4, *(const float4*)(wr + 4));
    }
  }
#pragma unroll
  for (int c = 0; c < 16; ++c) {
    float vq = tanhf(acc[c] + dec_b[j0 + c]);
    rnn_out[(size_t)row * HDIM + j0 + c] = f2bf(vq);
  }
}

// ---------- heads ----------
__global__ __launch_bounds__(256) void head_kernel(
    const ushort_t* __restrict__ rnn_out,
    const float* __restrict__ exp_w, const float* __restrict__ exp_b,
    const float* __restrict__ log_w, const float* __restrict__ log_b,
    float* __restrict__ outm, float* __restrict__ outv)
{
  const int lane = threadIdx.x & 63;
  const int wv   = threadIdx.x >> 6;
  const int row = blockIdx.x * 64 + lane;
  const int c0  = wv * 32;
  const ushort_t* a = rnn_out + (size_t)row * HDIM;
  const float* wmat = (c0 < 64) ? exp_w : log_w;
  const int cc0 = c0 & 63;

  float acc[32];
#pragma unroll
  for (int i = 0; i < 32; ++i) acc[i] = 0.f;

#pragma unroll 1
  for (int k = 0; k < HDIM; k += 8) {
    float af[8];
    uint4 v = *(const uint4*)(a + k);
    unpack8(v, af);
#pragma unroll
    for (int i = 0; i < 32; ++i) {
      const float* wr = wmat + (size_t)(cc0 + i) * HDIM + k;
      dot4(acc[i], af,     *(const float4*)wr);
      dot4(acc[i], af + 4, *(const float4*)(wr + 4));
    }
  }

  if (c0 < 64) {
#pragma unroll
    for (int i = 0; i < 32; ++i) {
      int y = cc0 + i;
      outm[(size_t)row * YDIM + y] = acc[i] + exp_b[y];
    }
  } else {
#pragma unroll
    for (int i = 0; i < 32; ++i) {
      int y = cc0 + i;
      outv[(size_t)row * YDIM + y] = expf(acc[i] + log_b[y]);
    }
  }
}

// ---------- host ----------
extern "C" void kernel_launch(void* const* d_in, const int* in_sizes, int n_in,
                              void* d_out, int out_size, void* d_ws, size_t ws_size,
                              hipStream_t stream) {
  (void)in_sizes; (void)n_in; (void)out_size; (void)ws_size;
  const float* x     = (const float*)d_in[0];
  const float* enc_w = (const float*)d_in[1];
  const float* enc_b = (const float*)d_in[2];
  const float* w_ih  = (const float*)d_in[3];
  const float* w_hh  = (const float*)d_in[4];
  const float* b_ih  = (const float*)d_in[5];
  const float* b_hh  = (const float*)d_in[6];
  const float* dec_w = (const float*)d_in[7];
  const float* dec_b = (const float*)d_in[8];
  const float* exp_w = (const float*)d_in[9];
  const float* exp_b = (const float*)d_in[10];
  const float* log_w = (const float*)d_in[11];
  const float* log_b = (const float*)d_in[12];
  float* out = (float*)d_out;

  char* ws = (char*)d_ws;
  ushort_t* h0s   = (ushort_t*)ws;                        // 256 KB
  ushort_t* h1s   = (ushort_t*)(ws + 262144);             // 256 KB
  float*    h0f   = (float*)(ws + 524288);                // 512 KB
  float*    h1f   = (float*)(ws + 1048576);               // 512 KB
  u32*      cnt   = (u32*)(ws + 1572864);                 // 513 u32 barrier counters
  ushort_t* wfrag = (ushort_t*)(ws + 2097152);            // 32 MB (reused as rnn_out staging)
  ushort_t* ench1 = (ushort_t*)(ws + 2097152 + 33554432); // 64 MB enc slices / h1_all

  hipMemsetAsync(ws, 0, 1576960, stream);  // h-state buffers + barrier counters

  enc_kernel<<<32768, 256, 0, stream>>>(x, enc_w, enc_b, ench1);
  wprep_kernel<<<8192, 256, 0, stream>>>(w_ih, w_hh, wfrag);

  {
    void* args[10];
    args[0] = (void*)&ench1;
    args[1] = (void*)&wfrag;
    args[2] = (void*)&b_ih;
    args[3] = (void*)&b_hh;
    args[4] = (void*)&h0s;
    args[5] = (void*)&h1s;
    args[6] = (void*)&h0f;
    args[7] = (void*)&h1f;
    args[8] = (void*)&ench1;
    args[9] = (void*)&cnt;
    hipLaunchCooperativeKernel((const void*)rnn_persist, dim3(256), dim3(512),
                               args, 0, stream);
  }

  ushort_t* staging = wfrag;
  for (int half = 0; half < 2; ++half) {
    const ushort_t* h1p = ench1 + (size_t)half * 16384 * HDIM;
    dec_kernel<<<4096, 256, 0, stream>>>(h1p, dec_w, dec_b, staging);
    float* outm = out + (size_t)half * 16384 * YDIM;
    float* outv = out + (size_t)T_STEPS * BATCH * YDIM + (size_t)half * 16384 * YDIM;
    head_kernel<<<256, 256, 0, stream>>>(staging, exp_w, exp_b, log_w, log_b, outm, outv);
  }
}

// Round 6
// 17126.483 us; speedup vs baseline: 1.0145x; 1.0038x over previous
//
#include <hip/hip_runtime.h>
#include <hip/hip_bf16.h>
#include <cstdint>

#define T_STEPS 512
#define BATCH   64
#define XDIM    64
#define HDIM    1024
#define YDIM    64

// per-block weight slice in LDS: 4 combos x (16KB rz + 8KB n) = 96KB
#define WBLK_BYTES   98304
#define COMBO_BYTES  24576
#define TL1_OFF      16384

typedef unsigned short ushort_t;
typedef uint32_t u32;
typedef unsigned long long u64;
typedef __attribute__((ext_vector_type(8))) short short8;
typedef __attribute__((ext_vector_type(4))) float f32x4;

// ---------- helpers ----------
__device__ __forceinline__ void unpack8(const uint4 v, float* f) {
  f[0] = __uint_as_float(v.x << 16);
  f[1] = __uint_as_float(v.x & 0xffff0000u);
  f[2] = __uint_as_float(v.y << 16);
  f[3] = __uint_as_float(v.y & 0xffff0000u);
  f[4] = __uint_as_float(v.z << 16);
  f[5] = __uint_as_float(v.z & 0xffff0000u);
  f[6] = __uint_as_float(v.w << 16);
  f[7] = __uint_as_float(v.w & 0xffff0000u);
}

__device__ __forceinline__ u32 f2bf_u(float x) {
  u32 u = __float_as_uint(x);
  return (u + 0x7fffu + ((u >> 16) & 1u)) >> 16;  // round-nearest-even
}
__device__ __forceinline__ ushort_t f2bf(float x) { return (ushort_t)f2bf_u(x); }

__device__ __forceinline__ float sigm(float x) { return 1.0f / (1.0f + expf(-x)); }

__device__ __forceinline__ void dot4(float& acc, const float* a, const float4 w) {
  acc = fmaf(a[0], w.x, acc);
  acc = fmaf(a[1], w.y, acc);
  acc = fmaf(a[2], w.z, acc);
  acc = fmaf(a[3], w.w, acc);
}

// ---------- coherence-point (sc1) access helpers: no cache maintenance ----------
__device__ __forceinline__ u64 ld_sc64(const ushort_t* p) {
  return __hip_atomic_load((u64*)p, __ATOMIC_RELAXED, __HIP_MEMORY_SCOPE_AGENT);
}
__device__ __forceinline__ float ld_scf(const float* p) {
  return __hip_atomic_load((float*)p, __ATOMIC_RELAXED, __HIP_MEMORY_SCOPE_AGENT);
}
__device__ __forceinline__ void st_sc32(u32* p, u32 v) {
  __hip_atomic_store(p, v, __ATOMIC_RELAXED, __HIP_MEMORY_SCOPE_AGENT);
}
__device__ __forceinline__ void st_scf(float* p, float v) {
  __hip_atomic_store(p, v, __ATOMIC_RELAXED, __HIP_MEMORY_SCOPE_AGENT);
}
__device__ __forceinline__ short8 ldA_sc(const ushort_t* p) {
  union { short8 s; u64 q[2]; } u;
  u.q[0] = ld_sc64(p);
  u.q[1] = ld_sc64(p + 4);
  return u.s;
}

// ---------- encoder ----------
__global__ __launch_bounds__(256) void enc_kernel(
    const float* __restrict__ x, const float* __restrict__ enc_w,
    const float* __restrict__ enc_b, ushort_t* __restrict__ enc_out)
{
  const int lane = threadIdx.x & 63;
  const int wv   = threadIdx.x >> 6;
  const int cb = blockIdx.x & 15;
  const int rb = blockIdx.x >> 4;
  const int j  = cb * 64 + lane;
  const int r0 = rb * 16 + wv * 4;
  const float* wrow = enc_w + (size_t)j * XDIM;
  const float* xr   = x + (size_t)r0 * XDIM;
  float acc[4] = {0.f, 0.f, 0.f, 0.f};
#pragma unroll
  for (int k = 0; k < XDIM; k += 4) {
    float4 w4 = *(const float4*)(wrow + k);
#pragma unroll
    for (int rr = 0; rr < 4; ++rr) {
      float4 xv = *(const float4*)(xr + rr * XDIM + k);
      acc[rr] = fmaf(xv.x, w4.x, acc[rr]);
      acc[rr] = fmaf(xv.y, w4.y, acc[rr]);
      acc[rr] = fmaf(xv.z, w4.z, acc[rr]);
      acc[rr] = fmaf(xv.w, w4.w, acc[rr]);
    }
  }
  float b = enc_b[j];
#pragma unroll
  for (int rr = 0; rr < 4; ++rr)
    enc_out[(size_t)(r0 + rr) * HDIM + j] = f2bf(tanhf(acc[rr] + b));
}

// ---------- weight pre-pack into per-block LDS image ----------
// wave-task c = bid*128 + c2*32 + tl*16 + ko;  c2 = g*2+kh
// tl=0: full chunk 1KB ([r|z] cols), lane=kgrp*16+col
// tl=1: compact 512B (n cols only), active lanes 0..31: kgrp=l>>3, col=l&7
__global__ __launch_bounds__(256) void wprep_kernel(
    const float* __restrict__ w_ih, const float* __restrict__ w_hh,
    ushort_t* __restrict__ wfrag)
{
  const int lane = threadIdx.x & 63;
  const int wv   = threadIdx.x >> 6;
  const int c    = blockIdx.x * 4 + wv;
  const int ko = c & 15;
  const int tl = (c >> 4) & 1;
  const int c2 = (c >> 5) & 3;
  const int bid = c >> 7;
  const int g = c2 >> 1, kh = c2 & 1;
  const int layer = bid >> 7;
  const int j0 = (bid & 127) * 8;
  const float* wsrc = (g ? w_hh : w_ih) + (size_t)layer * 3 * HDIM * HDIM;

  if (tl == 0) {
    const int col = lane & 15, kgrp = lane >> 4;
    const int k = kh * 512 + ko * 32 + kgrp * 8;
    const int row = (col < 8) ? (j0 + col) : (HDIM + j0 + col - 8);
    const float* src = wsrc + (size_t)row * HDIM + k;
    short8 v;
#pragma unroll
    for (int e = 0; e < 8; ++e) v[e] = (short)f2bf(src[e]);
    const size_t byte = (size_t)bid * WBLK_BYTES + c2 * COMBO_BYTES + ko * 1024 + lane * 16;
    *(short8*)((char*)wfrag + byte) = v;
  } else if (lane < 32) {
    const int kgrp = lane >> 3, col = lane & 7;
    const int k = kh * 512 + ko * 32 + kgrp * 8;
    const int row = 2 * HDIM + j0 + col;
    const float* src = wsrc + (size_t)row * HDIM + k;
    short8 v;
#pragma unroll
    for (int e = 0; e < 8; ++e) v[e] = (short)f2bf(src[e]);
    const size_t byte = (size_t)bid * WBLK_BYTES + c2 * COMBO_BYTES + TL1_OFF + ko * 512 + lane * 16;
    *(short8*)((char*)wfrag + byte) = v;
  }
}

// ---------- fence-free grid barrier ----------
__device__ __forceinline__ void gbar(u32* cnt, int phase) {
  __syncthreads();
  if (threadIdx.x == 0) {
    u32* p = cnt + phase;
    __hip_atomic_fetch_add(p, 1u, __ATOMIC_RELAXED, __HIP_MEMORY_SCOPE_AGENT);
    while (__hip_atomic_load(p, __ATOMIC_RELAXED, __HIP_MEMORY_SCOPE_AGENT) < 256u)
      __builtin_amdgcn_s_sleep(2);
  }
  __syncthreads();
}

// ---------- persistent recurrent kernel (weights in LDS) ----------
// 256 blocks x 512 threads, 1 block/CU. Block bid: layer=bid>>7, h-cols j0=(bid&127)*8.
// Wave: mp=wid&1 (m-pair), g=(wid>>1)&1 (ih/hh), kh=wid>>2 (K half).
__global__ __launch_bounds__(512, 1) void rnn_persist(
    const ushort_t* __restrict__ ench1,   // enc slices; slice t overwritten by h1(t)
    const ushort_t* __restrict__ wfrag,
    const float* __restrict__ b_ih, const float* __restrict__ b_hh,
    ushort_t* __restrict__ h0s, ushort_t* __restrict__ h1s,
    float* __restrict__ h0f, float* __restrict__ h1f,
    ushort_t* __restrict__ h1_all,        // == ench1
    u32* __restrict__ cnt)
{
  extern __shared__ char smem[];          // 96KB weights + 32KB exchange = 128KB
  float* lds_part = (float*)(smem + WBLK_BYTES);

  const int tid  = threadIdx.x;
  const int lane = tid & 63;
  const int wid  = tid >> 6;
  const int bid  = blockIdx.x;
  const int layer = bid >> 7;
  const int j0    = (bid & 127) * 8;
  const int mp = wid & 1, g = (wid >> 1) & 1, kh = wid >> 2;
  const int col = lane & 15, kgrp = lane >> 4;
  const bool isL1 = (layer == 1);

  // ---- one-time: stage this block's 96KB weight image into LDS ----
  {
    const uint4* src = (const uint4*)((const char*)wfrag + (size_t)bid * WBLK_BYTES);
    uint4* dst = (uint4*)smem;
#pragma unroll 4
    for (int i = tid; i < WBLK_BYTES / 16; i += 512) dst[i] = src[i];
  }

  // per-wave LDS fragment addresses
  const int c2 = g * 2 + kh;
  const char* w0 = smem + c2 * COMBO_BYTES + lane * 16;                        // tl0: +ko*1024
  const char* w1 = smem + c2 * COMBO_BYTES + TL1_OFF + (kgrp * 8 + (col & 7)) * 16;  // tl1: +ko*512

  // ---- biases ----
  float bA = 0.f, bB = 0.f, bC = 0.f;
  {
    const float* bi = b_ih + layer * 3 * HDIM;
    const float* bh = b_hh + layer * 3 * HDIM;
    if (col < 8) {
      const int j = j0 + col;
      bA = bi[j] + bh[j];
      bB = bi[2 * HDIM + j];
      bC = bh[2 * HDIM + j];
    } else {
      const int j = j0 + col - 8;
      bA = bi[HDIM + j] + bh[HDIM + j];
    }
  }
  __syncthreads();  // LDS weight image ready

  for (int s = 0; s <= T_STEPS; ++s) {
    const bool active = isL1 ? (s >= 1) : (s < T_STEPS);
    if (active) {
      const int t = isL1 ? (s - 1) : s;
      const ushort_t* A1 = isL1 ? (h0s + ((s + 1) & 1) * (BATCH * HDIM))
                                : (ench1 + (size_t)t * (BATCH * HDIM));
      const ushort_t* A2 = isL1 ? (h1s + (s & 1) * (BATCH * HDIM))
                                : (h0s + ((s + 1) & 1) * (BATCH * HDIM));
      const ushort_t* A = g ? A2 : A1;
      const bool coh = !(layer == 0 && g == 0);  // enc slices plain-cacheable

      f32x4 acc00 = {0,0,0,0}, acc01 = {0,0,0,0}, acc10 = {0,0,0,0}, acc11 = {0,0,0,0};
      const ushort_t* Arow0 = A + (size_t)(mp * 32 + col) * HDIM + kh * 512 + kgrp * 8;
      const ushort_t* Arow1 = Arow0 + 16 * HDIM;
#pragma unroll
      for (int ko = 0; ko < 16; ++ko) {
        const short8 b0 = *(const short8*)(w0 + ko * 1024);
        const short8 b1 = *(const short8*)(w1 + ko * 512);   // cols>=8: garbage, C-cols unused
        short8 a0, a1;
        if (coh) { a0 = ldA_sc(Arow0 + ko * 32); a1 = ldA_sc(Arow1 + ko * 32); }
        else     { a0 = *(const short8*)(Arow0 + ko * 32); a1 = *(const short8*)(Arow1 + ko * 32); }
        acc00 = __builtin_amdgcn_mfma_f32_16x16x32_bf16(a0, b0, acc00, 0, 0, 0);
        acc01 = __builtin_amdgcn_mfma_f32_16x16x32_bf16(a0, b1, acc01, 0, 0, 0);
        acc10 = __builtin_amdgcn_mfma_f32_16x16x32_bf16(a1, b0, acc10, 0, 0, 0);
        acc11 = __builtin_amdgcn_mfma_f32_16x16x32_bf16(a1, b1, acc11, 0, 0, 0);
      }
      const int base = (wid * 4) * 256 + lane * 4;
      *(f32x4*)&lds_part[base      ] = acc00;
      *(f32x4*)&lds_part[base + 256] = acc01;
      *(f32x4*)&lds_part[base + 512] = acc10;
      *(f32x4*)&lds_part[base + 768] = acc11;
    }
    __syncthreads();

    if (active && wid < 4) {
      const int m = wid, mpe = m >> 1, ime = m & 1;
      const int i00 = ((0 * 4 + 0 * 2 + mpe) * 4 + ime * 2);
      const int i01 = ((1 * 4 + 0 * 2 + mpe) * 4 + ime * 2);
      const int i10 = ((0 * 4 + 1 * 2 + mpe) * 4 + ime * 2);
      const int i11 = ((1 * 4 + 1 * 2 + mpe) * 4 + ime * 2);
      const int lo = lane * 4;
      f32x4 girz = *(f32x4*)&lds_part[i00 * 256 + lo] + *(f32x4*)&lds_part[i01 * 256 + lo];
      f32x4 gin  = *(f32x4*)&lds_part[(i00 + 1) * 256 + lo] + *(f32x4*)&lds_part[(i01 + 1) * 256 + lo];
      f32x4 ghrz = *(f32x4*)&lds_part[i10 * 256 + lo] + *(f32x4*)&lds_part[i11 * 256 + lo];
      f32x4 ghn  = *(f32x4*)&lds_part[(i10 + 1) * 256 + lo] + *(f32x4*)&lds_part[(i11 + 1) * 256 + lo];

      const int s1 = (s + 1) & 1, s0 = s & 1;
      const float* hpf = isL1 ? (h1f + s0 * (BATCH * HDIM)) : (h0f + s1 * (BATCH * HDIM));
      float* hfd       = isL1 ? (h1f + s1 * (BATCH * HDIM)) : (h0f + s0 * (BATCH * HDIM));
      ushort_t* hdst   = isL1 ? (h1s + s1 * (BATCH * HDIM)) : (h0s + s0 * (BATCH * HDIM));
      ushort_t* hall   = isL1 ? (h1_all + (size_t)(s - 1) * (BATCH * HDIM)) : (ushort_t*)0;

#pragma unroll
      for (int e = 0; e < 4; ++e) {
        const float rz = sigm(girz[e] + ghrz[e] + bA);
        const float nv = tanhf(gin[e] + bB + rz * (ghn[e] + bC));
        const float zv = __shfl_xor(rz, 8);
        const int b = m * 16 + kgrp * 4 + e;
        float h = 0.f;
        if (col < 8) {
          const float hpv = ld_scf(hpf + b * HDIM + j0 + col);
          h = (1.f - zv) * nv + zv * hpv;
          st_scf(hfd + b * HDIM + j0 + col, h);
        }
        const u32 hb = f2bf_u(h);
        const u32 pb = (u32)__shfl_xor((int)hb, 1);
        if (col < 8 && (col & 1) == 0) {
          const u32 pack = hb | (pb << 16);
          st_sc32((u32*)(hdst + b * HDIM + j0 + col), pack);
          if (hall) st_sc32((u32*)(hall + b * HDIM + j0 + col), pack);
        }
      }
    }
    if (s < T_STEPS) gbar(cnt, s);
  }
}

// ---------- decoder ----------
__global__ __launch_bounds__(256) void dec_kernel(
    const ushort_t* __restrict__ h1_all, const float* __restrict__ dec_w,
    const float* __restrict__ dec_b, ushort_t* __restrict__ rnn_out)
{
  const int lane = threadIdx.x & 63;
  const int wv   = threadIdx.x >> 6;
  const int cb = blockIdx.x & 15;
  const int rb = blockIdx.x >> 4;
  const int row = rb * 64 + lane;
  const int j0  = cb * 64 + wv * 16;
  const ushort_t* a = h1_all + (size_t)row * HDIM;
  float acc[16];
#pragma unroll
  for (int c = 0; c < 16; ++c) acc[c] = 0.f;

#pragma unroll 1
  for (int k = 0; k < HDIM; k += 8) {
    float af[8];
    uint4 v = *(const uint4*)(a + k);
    unpack8(v, af);
#pragma unroll
    for (int c = 0; c < 16; ++c) {
      const float* wr = dec_w + (size_t)(j0 + c) * HDIM + k;
      dot4(acc[c], af,     *(const float4*)wr);
      dot4(acc[c], af + 4, *(const float4*)(wr + 4));
    }
  }
#pragma unroll
  for (int c = 0; c < 16; ++c) {
    float vq = tanhf(acc[c] + dec_b[j0 + c]);
    rnn_out[(size_t)row * HDIM + j0 + c] = f2bf(vq);
  }
}

// ---------- heads ----------
__global__ __launch_bounds__(256) void head_kernel(
    const ushort_t* __restrict__ rnn_out,
    const float* __restrict__ exp_w, const float* __restrict__ exp_b,
    const float* __restrict__ log_w, const float* __restrict__ log_b,
    float* __restrict__ outm, float* __restrict__ outv)
{
  const int lane = threadIdx.x & 63;
  const int wv   = threadIdx.x >> 6;
  const int row = blockIdx.x * 64 + lane;
  const int c0  = wv * 32;
  const ushort_t* a = rnn_out + (size_t)row * HDIM;
  const float* wmat = (c0 < 64) ? exp_w : log_w;
  const int cc0 = c0 & 63;

  float acc[32];
#pragma unroll
  for (int i = 0; i < 32; ++i) acc[i] = 0.f;

#pragma unroll 1
  for (int k = 0; k < HDIM; k += 8) {
    float af[8];
    uint4 v = *(const uint4*)(a + k);
    unpack8(v, af);
#pragma unroll
    for (int i = 0; i < 32; ++i) {
      const float* wr = wmat + (size_t)(cc0 + i) * HDIM + k;
      dot4(acc[i], af,     *(const float4*)wr);
      dot4(acc[i], af + 4, *(const float4*)(wr + 4));
    }
  }

  if (c0 < 64) {
#pragma unroll
    for (int i = 0; i < 32; ++i) {
      int y = cc0 + i;
      outm[(size_t)row * YDIM + y] = acc[i] + exp_b[y];
    }
  } else {
#pragma unroll
    for (int i = 0; i < 32; ++i) {
      int y = cc0 + i;
      outv[(size_t)row * YDIM + y] = expf(acc[i] + log_b[y]);
    }
  }
}

// ---------- host ----------
extern "C" void kernel_launch(void* const* d_in, const int* in_sizes, int n_in,
                              void* d_out, int out_size, void* d_ws, size_t ws_size,
                              hipStream_t stream) {
  (void)in_sizes; (void)n_in; (void)out_size; (void)ws_size;
  const float* x     = (const float*)d_in[0];
  const float* enc_w = (const float*)d_in[1];
  const float* enc_b = (const float*)d_in[2];
  const float* w_ih  = (const float*)d_in[3];
  const float* w_hh  = (const float*)d_in[4];
  const float* b_ih  = (const float*)d_in[5];
  const float* b_hh  = (const float*)d_in[6];
  const float* dec_w = (const float*)d_in[7];
  const float* dec_b = (const float*)d_in[8];
  const float* exp_w = (const float*)d_in[9];
  const float* exp_b = (const float*)d_in[10];
  const float* log_w = (const float*)d_in[11];
  const float* log_b = (const float*)d_in[12];
  float* out = (float*)d_out;

  char* ws = (char*)d_ws;
  ushort_t* h0s   = (ushort_t*)ws;                        // 256 KB
  ushort_t* h1s   = (ushort_t*)(ws + 262144);             // 256 KB
  float*    h0f   = (float*)(ws + 524288);                // 512 KB
  float*    h1f   = (float*)(ws + 1048576);               // 512 KB
  u32*      cnt   = (u32*)(ws + 1572864);                 // 513 u32 barrier counters
  ushort_t* wfrag = (ushort_t*)(ws + 2097152);            // 24 MB used (32 MB reserved; reused as staging)
  ushort_t* ench1 = (ushort_t*)(ws + 2097152 + 33554432); // 64 MB enc slices / h1_all

  hipMemsetAsync(ws, 0, 1576960, stream);  // h-state buffers + barrier counters

  enc_kernel<<<32768, 256, 0, stream>>>(x, enc_w, enc_b, ench1);
  wprep_kernel<<<8192, 256, 0, stream>>>(w_ih, w_hh, wfrag);

  {
    static int lds_opted = 0;
    if (!lds_opted) {  // idempotent host-side attribute; not a stream op
      hipFuncSetAttribute((const void*)rnn_persist,
                          hipFuncAttributeMaxDynamicSharedMemorySize, 131072);
      lds_opted = 1;
    }
    void* args[10];
    args[0] = (void*)&ench1;
    args[1] = (void*)&wfrag;
    args[2] = (void*)&b_ih;
    args[3] = (void*)&b_hh;
    args[4] = (void*)&h0s;
    args[5] = (void*)&h1s;
    args[6] = (void*)&h0f;
    args[7] = (void*)&h1f;
    args[8] = (void*)&ench1;
    args[9] = (void*)&cnt;
    hipLaunchCooperativeKernel((const void*)rnn_persist, dim3(256), dim3(512),
                               args, 131072, stream);
  }

  ushort_t* staging = wfrag;
  for (int half = 0; half < 2; ++half) {
    const ushort_t* h1p = ench1 + (size_t)half * 16384 * HDIM;
    dec_kernel<<<4096, 256, 0, stream>>>(h1p, dec_w, dec_b, staging);
    float* outm = out + (size_t)half * 16384 * YDIM;
    float* outv = out + (size_t)T_STEPS * BATCH * YDIM + (size_t)half * 16384 * YDIM;
    head_kernel<<<256, 256, 0, stream>>>(staging, exp_w, exp_b, log_w, log_b, outm, outv);
  }
}

// Round 7
// 14036.259 us; speedup vs baseline: 1.2378x; 1.2202x over previous
//
#include <hip/hip_runtime.h>
#include <hip/hip_bf16.h>
#include <cstdint>

#define T_STEPS 512
#define BATCH   64
#define XDIM    64
#define HDIM    1024
#define YDIM    64

// per-block weight slice in LDS: 4 combos x (16KB rz + 8KB n) = 96KB
#define WBLK_BYTES   98304
#define COMBO_BYTES  24576
#define TL1_OFF      16384

typedef unsigned short ushort_t;
typedef uint32_t u32;
typedef unsigned long long u64;
typedef __attribute__((ext_vector_type(8))) short short8;
typedef __attribute__((ext_vector_type(4))) float f32x4;

// ---------- helpers ----------
__device__ __forceinline__ void unpack8(const uint4 v, float* f) {
  f[0] = __uint_as_float(v.x << 16);
  f[1] = __uint_as_float(v.x & 0xffff0000u);
  f[2] = __uint_as_float(v.y << 16);
  f[3] = __uint_as_float(v.y & 0xffff0000u);
  f[4] = __uint_as_float(v.z << 16);
  f[5] = __uint_as_float(v.z & 0xffff0000u);
  f[6] = __uint_as_float(v.w << 16);
  f[7] = __uint_as_float(v.w & 0xffff0000u);
}

__device__ __forceinline__ u32 f2bf_u(float x) {
  u32 u = __float_as_uint(x);
  return (u + 0x7fffu + ((u >> 16) & 1u)) >> 16;  // round-nearest-even
}
__device__ __forceinline__ ushort_t f2bf(float x) { return (ushort_t)f2bf_u(x); }

__device__ __forceinline__ float sigm(float x) { return 1.0f / (1.0f + expf(-x)); }

__device__ __forceinline__ void dot4(float& acc, const float* a, const float4 w) {
  acc = fmaf(a[0], w.x, acc);
  acc = fmaf(a[1], w.y, acc);
  acc = fmaf(a[2], w.z, acc);
  acc = fmaf(a[3], w.w, acc);
}

// ---------- coherence-point (sc1) access helpers ----------
__device__ __forceinline__ u64 ld_sc64(const ushort_t* p) {
  return __hip_atomic_load((u64*)p, __ATOMIC_RELAXED, __HIP_MEMORY_SCOPE_AGENT);
}
__device__ __forceinline__ void st_sc32(u32* p, u32 v) {
  __hip_atomic_store(p, v, __ATOMIC_RELAXED, __HIP_MEMORY_SCOPE_AGENT);
}
__device__ __forceinline__ u32 ld_sc32(const u32* p) {
  return __hip_atomic_load((u32*)p, __ATOMIC_RELAXED, __HIP_MEMORY_SCOPE_AGENT);
}
__device__ __forceinline__ short8 ldA_sc(const ushort_t* p) {
  union { short8 s; u64 q[2]; } u;
  u.q[0] = ld_sc64(p);
  u.q[1] = ld_sc64(p + 4);
  return u.s;
}

// ---------- encoder ----------
__global__ __launch_bounds__(256) void enc_kernel(
    const float* __restrict__ x, const float* __restrict__ enc_w,
    const float* __restrict__ enc_b, ushort_t* __restrict__ enc_out)
{
  const int lane = threadIdx.x & 63;
  const int wv   = threadIdx.x >> 6;
  const int cb = blockIdx.x & 15;
  const int rb = blockIdx.x >> 4;
  const int j  = cb * 64 + lane;
  const int r0 = rb * 16 + wv * 4;
  const float* wrow = enc_w + (size_t)j * XDIM;
  const float* xr   = x + (size_t)r0 * XDIM;
  float acc[4] = {0.f, 0.f, 0.f, 0.f};
#pragma unroll
  for (int k = 0; k < XDIM; k += 4) {
    float4 w4 = *(const float4*)(wrow + k);
#pragma unroll
    for (int rr = 0; rr < 4; ++rr) {
      float4 xv = *(const float4*)(xr + rr * XDIM + k);
      acc[rr] = fmaf(xv.x, w4.x, acc[rr]);
      acc[rr] = fmaf(xv.y, w4.y, acc[rr]);
      acc[rr] = fmaf(xv.z, w4.z, acc[rr]);
      acc[rr] = fmaf(xv.w, w4.w, acc[rr]);
    }
  }
  float b = enc_b[j];
#pragma unroll
  for (int rr = 0; rr < 4; ++rr)
    enc_out[(size_t)(r0 + rr) * HDIM + j] = f2bf(tanhf(acc[rr] + b));
}

// ---------- weight pre-pack into per-block LDS image ----------
__global__ __launch_bounds__(256) void wprep_kernel(
    const float* __restrict__ w_ih, const float* __restrict__ w_hh,
    ushort_t* __restrict__ wfrag)
{
  const int lane = threadIdx.x & 63;
  const int wv   = threadIdx.x >> 6;
  const int c    = blockIdx.x * 4 + wv;
  const int ko = c & 15;
  const int tl = (c >> 4) & 1;
  const int c2 = (c >> 5) & 3;
  const int bid = c >> 7;
  const int g = c2 >> 1, kh = c2 & 1;
  const int layer = bid >> 7;
  const int j0 = (bid & 127) * 8;
  const float* wsrc = (g ? w_hh : w_ih) + (size_t)layer * 3 * HDIM * HDIM;

  if (tl == 0) {
    const int col = lane & 15, kgrp = lane >> 4;
    const int k = kh * 512 + ko * 32 + kgrp * 8;
    const int row = (col < 8) ? (j0 + col) : (HDIM + j0 + col - 8);
    const float* src = wsrc + (size_t)row * HDIM + k;
    short8 v;
#pragma unroll
    for (int e = 0; e < 8; ++e) v[e] = (short)f2bf(src[e]);
    const size_t byte = (size_t)bid * WBLK_BYTES + c2 * COMBO_BYTES + ko * 1024 + lane * 16;
    *(short8*)((char*)wfrag + byte) = v;
  } else if (lane < 32) {
    const int kgrp = lane >> 3, col = lane & 7;
    const int k = kh * 512 + ko * 32 + kgrp * 8;
    const int row = 2 * HDIM + j0 + col;
    const float* src = wsrc + (size_t)row * HDIM + k;
    short8 v;
#pragma unroll
    for (int e = 0; e < 8; ++e) v[e] = (short)f2bf(src[e]);
    const size_t byte = (size_t)bid * WBLK_BYTES + c2 * COMBO_BYTES + TL1_OFF + ko * 512 + lane * 16;
    *(short8*)((char*)wfrag + byte) = v;
  }
}

// ---------- atomic-free grid barrier: per-block flag lines + release word ----------
// flags[bid] at 256B stride. Arrival = ONE plain sc1 store (no RMW serialization).
// Block 0's threads 0..255 poll all flags in parallel, then publish release.
// __syncthreads before arrival drains vmcnt -> all sc1 data stores are at the
// coherence point before the flag becomes visible (same ordering rounds 4-6
// relied on, verified passing).
__device__ __forceinline__ void gbar2(u32* flags, u32* release, int s) {
  const u32 tag = (u32)s + 1u;
  const int tid = threadIdx.x;
  __syncthreads();
  if (tid == 0) st_sc32(flags + (size_t)blockIdx.x * 64, tag);
  if (blockIdx.x == 0) {
    if (tid < 256) {
      u32* fp = flags + (size_t)tid * 64;
      while (ld_sc32(fp) < tag) __builtin_amdgcn_s_sleep(1);
    }
    __syncthreads();
    if (tid == 0) st_sc32(release, tag);
  } else {
    if (tid == 0) {
      while (ld_sc32(release) < tag) __builtin_amdgcn_s_sleep(1);
    }
    __syncthreads();
  }
}

// ---------- persistent recurrent kernel (weights in LDS, fp32 state in regs) ----------
__global__ __launch_bounds__(512, 1) void rnn_persist(
    const ushort_t* __restrict__ ench1,   // enc slices; slice t overwritten by h1(t)
    const ushort_t* __restrict__ wfrag,
    const float* __restrict__ b_ih, const float* __restrict__ b_hh,
    ushort_t* __restrict__ h0s, ushort_t* __restrict__ h1s,
    ushort_t* __restrict__ h1_all,        // == ench1
    u32* __restrict__ flags, u32* __restrict__ release)
{
  extern __shared__ char smem[];          // 96KB weights + 32KB exchange = 128KB
  float* lds_part = (float*)(smem + WBLK_BYTES);

  const int tid  = threadIdx.x;
  const int lane = tid & 63;
  const int wid  = tid >> 6;
  const int bid  = blockIdx.x;
  const int layer = bid >> 7;
  const int j0    = (bid & 127) * 8;
  const int mp = wid & 1, g = (wid >> 1) & 1, kh = wid >> 2;
  const int col = lane & 15, kgrp = lane >> 4;
  const bool isL1 = (layer == 1);

  // ---- one-time: stage this block's 96KB weight image into LDS ----
  {
    const uint4* src = (const uint4*)((const char*)wfrag + (size_t)bid * WBLK_BYTES);
    uint4* dst = (uint4*)smem;
#pragma unroll 4
    for (int i = tid; i < WBLK_BYTES / 16; i += 512) dst[i] = src[i];
  }

  const int c2 = g * 2 + kh;
  const char* w0 = smem + c2 * COMBO_BYTES + lane * 16;
  const char* w1 = smem + c2 * COMBO_BYTES + TL1_OFF + (kgrp * 8 + (col & 7)) * 16;

  // ---- biases ----
  float bA = 0.f, bB = 0.f, bC = 0.f;
  {
    const float* bi = b_ih + layer * 3 * HDIM;
    const float* bh = b_hh + layer * 3 * HDIM;
    if (col < 8) {
      const int j = j0 + col;
      bA = bi[j] + bh[j];
      bB = bi[2 * HDIM + j];
      bC = bh[2 * HDIM + j];
    } else {
      const int j = j0 + col - 8;
      bA = bi[HDIM + j] + bh[HDIM + j];
    }
  }

  f32x4 hp = {0.f, 0.f, 0.f, 0.f};  // running fp32 h-state (waves 0-3, col<8)

  __syncthreads();  // LDS weight image ready

  for (int s = 0; s <= T_STEPS; ++s) {
    const bool active = isL1 ? (s >= 1) : (s < T_STEPS);
    if (active) {
      const int t = isL1 ? (s - 1) : s;
      const ushort_t* A1 = isL1 ? (h0s + ((s + 1) & 1) * (BATCH * HDIM))
                                : (ench1 + (size_t)t * (BATCH * HDIM));
      const ushort_t* A2 = isL1 ? (h1s + (s & 1) * (BATCH * HDIM))
                                : (h0s + ((s + 1) & 1) * (BATCH * HDIM));
      const ushort_t* A = g ? A2 : A1;
      const bool coh = !(layer == 0 && g == 0);  // enc slices plain-cacheable

      f32x4 acc00 = {0,0,0,0}, acc01 = {0,0,0,0}, acc10 = {0,0,0,0}, acc11 = {0,0,0,0};
      const ushort_t* Arow0 = A + (size_t)(mp * 32 + col) * HDIM + kh * 512 + kgrp * 8;
      const ushort_t* Arow1 = Arow0 + 16 * HDIM;
#pragma unroll
      for (int ko = 0; ko < 16; ++ko) {
        const short8 b0 = *(const short8*)(w0 + ko * 1024);
        const short8 b1 = *(const short8*)(w1 + ko * 512);
        short8 a0, a1;
        if (coh) { a0 = ldA_sc(Arow0 + ko * 32); a1 = ldA_sc(Arow1 + ko * 32); }
        else     { a0 = *(const short8*)(Arow0 + ko * 32); a1 = *(const short8*)(Arow1 + ko * 32); }
        acc00 = __builtin_amdgcn_mfma_f32_16x16x32_bf16(a0, b0, acc00, 0, 0, 0);
        acc01 = __builtin_amdgcn_mfma_f32_16x16x32_bf16(a0, b1, acc01, 0, 0, 0);
        acc10 = __builtin_amdgcn_mfma_f32_16x16x32_bf16(a1, b0, acc10, 0, 0, 0);
        acc11 = __builtin_amdgcn_mfma_f32_16x16x32_bf16(a1, b1, acc11, 0, 0, 0);
      }
      const int base = (wid * 4) * 256 + lane * 4;
      *(f32x4*)&lds_part[base      ] = acc00;
      *(f32x4*)&lds_part[base + 256] = acc01;
      *(f32x4*)&lds_part[base + 512] = acc10;
      *(f32x4*)&lds_part[base + 768] = acc11;
    }
    __syncthreads();

    if (active && wid < 4) {
      const int m = wid, mpe = m >> 1, ime = m & 1;
      const int i00 = ((0 * 4 + 0 * 2 + mpe) * 4 + ime * 2);
      const int i01 = ((1 * 4 + 0 * 2 + mpe) * 4 + ime * 2);
      const int i10 = ((0 * 4 + 1 * 2 + mpe) * 4 + ime * 2);
      const int i11 = ((1 * 4 + 1 * 2 + mpe) * 4 + ime * 2);
      const int lo = lane * 4;
      f32x4 girz = *(f32x4*)&lds_part[i00 * 256 + lo] + *(f32x4*)&lds_part[i01 * 256 + lo];
      f32x4 gin  = *(f32x4*)&lds_part[(i00 + 1) * 256 + lo] + *(f32x4*)&lds_part[(i01 + 1) * 256 + lo];
      f32x4 ghrz = *(f32x4*)&lds_part[i10 * 256 + lo] + *(f32x4*)&lds_part[i11 * 256 + lo];
      f32x4 ghn  = *(f32x4*)&lds_part[(i10 + 1) * 256 + lo] + *(f32x4*)&lds_part[(i11 + 1) * 256 + lo];

      const int s1 = (s + 1) & 1, s0 = s & 1;
      ushort_t* hdst = isL1 ? (h1s + s1 * (BATCH * HDIM)) : (h0s + s0 * (BATCH * HDIM));
      ushort_t* hall = isL1 ? (h1_all + (size_t)(s - 1) * (BATCH * HDIM)) : (ushort_t*)0;

#pragma unroll
      for (int e = 0; e < 4; ++e) {
        const float rz = sigm(girz[e] + ghrz[e] + bA);
        const float nv = tanhf(gin[e] + bB + rz * (ghn[e] + bC));
        const float zv = __shfl_xor(rz, 8);
        const int b = m * 16 + kgrp * 4 + e;
        float h = 0.f;
        if (col < 8) {
          h = (1.f - zv) * nv + zv * hp[e];
          hp[e] = h;
        }
        const u32 hb = f2bf_u(h);
        const u32 pb = (u32)__shfl_xor((int)hb, 1);
        if (col < 8 && (col & 1) == 0) {
          const u32 pack = hb | (pb << 16);
          st_sc32((u32*)(hdst + b * HDIM + j0 + col), pack);
          if (hall) st_sc32((u32*)(hall + b * HDIM + j0 + col), pack);
        }
      }
    }
    if (s < T_STEPS) gbar2(flags, release, s);
  }
}

// ---------- decoder ----------
__global__ __launch_bounds__(256) void dec_kernel(
    const ushort_t* __restrict__ h1_all, const float* __restrict__ dec_w,
    const float* __restrict__ dec_b, ushort_t* __restrict__ rnn_out)
{
  const int lane = threadIdx.x & 63;
  const int wv   = threadIdx.x >> 6;
  const int cb = blockIdx.x & 15;
  const int rb = blockIdx.x >> 4;
  const int row = rb * 64 + lane;
  const int j0  = cb * 64 + wv * 16;
  const ushort_t* a = h1_all + (size_t)row * HDIM;
  float acc[16];
#pragma unroll
  for (int c = 0; c < 16; ++c) acc[c] = 0.f;

#pragma unroll 1
  for (int k = 0; k < HDIM; k += 8) {
    float af[8];
    uint4 v = *(const uint4*)(a + k);
    unpack8(v, af);
#pragma unroll
    for (int c = 0; c < 16; ++c) {
      const float* wr = dec_w + (size_t)(j0 + c) * HDIM + k;
      dot4(acc[c], af,     *(const float4*)wr);
      dot4(acc[c], af + 4, *(const float4*)(wr + 4));
    }
  }
#pragma unroll
  for (int c = 0; c < 16; ++c) {
    float vq = tanhf(acc[c] + dec_b[j0 + c]);
    rnn_out[(size_t)row * HDIM + j0 + c] = f2bf(vq);
  }
}

// ---------- heads ----------
__global__ __launch_bounds__(256) void head_kernel(
    const ushort_t* __restrict__ rnn_out,
    const float* __restrict__ exp_w, const float* __restrict__ exp_b,
    const float* __restrict__ log_w, const float* __restrict__ log_b,
    float* __restrict__ outm, float* __restrict__ outv)
{
  const int lane = threadIdx.x & 63;
  const int wv   = threadIdx.x >> 6;
  const int row = blockIdx.x * 64 + lane;
  const int c0  = wv * 32;
  const ushort_t* a = rnn_out + (size_t)row * HDIM;
  const float* wmat = (c0 < 64) ? exp_w : log_w;
  const int cc0 = c0 & 63;

  float acc[32];
#pragma unroll
  for (int i = 0; i < 32; ++i) acc[i] = 0.f;

#pragma unroll 1
  for (int k = 0; k < HDIM; k += 8) {
    float af[8];
    uint4 v = *(const uint4*)(a + k);
    unpack8(v, af);
#pragma unroll
    for (int i = 0; i < 32; ++i) {
      const float* wr = wmat + (size_t)(cc0 + i) * HDIM + k;
      dot4(acc[i], af,     *(const float4*)wr);
      dot4(acc[i], af + 4, *(const float4*)(wr + 4));
    }
  }

  if (c0 < 64) {
#pragma unroll
    for (int i = 0; i < 32; ++i) {
      int y = cc0 + i;
      outm[(size_t)row * YDIM + y] = acc[i] + exp_b[y];
    }
  } else {
#pragma unroll
    for (int i = 0; i < 32; ++i) {
      int y = cc0 + i;
      outv[(size_t)row * YDIM + y] = expf(acc[i] + log_b[y]);
    }
  }
}

// ---------- host ----------
extern "C" void kernel_launch(void* const* d_in, const int* in_sizes, int n_in,
                              void* d_out, int out_size, void* d_ws, size_t ws_size,
                              hipStream_t stream) {
  (void)in_sizes; (void)n_in; (void)out_size; (void)ws_size;
  const float* x     = (const float*)d_in[0];
  const float* enc_w = (const float*)d_in[1];
  const float* enc_b = (const float*)d_in[2];
  const float* w_ih  = (const float*)d_in[3];
  const float* w_hh  = (const float*)d_in[4];
  const float* b_ih  = (const float*)d_in[5];
  const float* b_hh  = (const float*)d_in[6];
  const float* dec_w = (const float*)d_in[7];
  const float* dec_b = (const float*)d_in[8];
  const float* exp_w = (const float*)d_in[9];
  const float* exp_b = (const float*)d_in[10];
  const float* log_w = (const float*)d_in[11];
  const float* log_b = (const float*)d_in[12];
  float* out = (float*)d_out;

  char* ws = (char*)d_ws;
  ushort_t* h0s     = (ushort_t*)ws;                        // 256 KB
  ushort_t* h1s     = (ushort_t*)(ws + 262144);             // 256 KB
  u32*      flags   = (u32*)(ws + 524288);                  // 256 x 256B = 64 KB
  u32*      release = (u32*)(ws + 589824);                  // own line
  ushort_t* wfrag   = (ushort_t*)(ws + 2097152);            // 24 MB (reused as staging)
  ushort_t* ench1   = (ushort_t*)(ws + 2097152 + 33554432); // 64 MB enc slices / h1_all

  hipMemsetAsync(ws, 0, 655360, stream);  // h-state + flags + release

  enc_kernel<<<32768, 256, 0, stream>>>(x, enc_w, enc_b, ench1);
  wprep_kernel<<<8192, 256, 0, stream>>>(w_ih, w_hh, wfrag);

  {
    static int lds_opted = 0;
    if (!lds_opted) {
      hipFuncSetAttribute((const void*)rnn_persist,
                          hipFuncAttributeMaxDynamicSharedMemorySize, 131072);
      lds_opted = 1;
    }
    void* args[9];
    args[0] = (void*)&ench1;
    args[1] = (void*)&wfrag;
    args[2] = (void*)&b_ih;
    args[3] = (void*)&b_hh;
    args[4] = (void*)&h0s;
    args[5] = (void*)&h1s;
    args[6] = (void*)&ench1;
    args[7] = (void*)&flags;
    args[8] = (void*)&release;
    hipLaunchCooperativeKernel((const void*)rnn_persist, dim3(256), dim3(512),
                               args, 131072, stream);
  }

  ushort_t* staging = wfrag;
  for (int half = 0; half < 2; ++half) {
    const ushort_t* h1p = ench1 + (size_t)half * 16384 * HDIM;
    dec_kernel<<<4096, 256, 0, stream>>>(h1p, dec_w, dec_b, staging);
    float* outm = out + (size_t)half * 16384 * YDIM;
    float* outv = out + (size_t)T_STEPS * BATCH * YDIM + (size_t)half * 16384 * YDIM;
    head_kernel<<<256, 256, 0, stream>>>(staging, exp_w, exp_b, log_w, log_b, outm, outv);
  }
}

// Round 8
// 10974.734 us; speedup vs baseline: 1.5831x; 1.2790x over previous
//
#include <hip/hip_runtime.h>
#include <hip/hip_bf16.h>
#include <cstdint>

#define T_STEPS 512
#define BATCH   64
#define XDIM    64
#define HDIM    1024
#define YDIM    64
#define BH      (BATCH * HDIM)

// per-block weight slice in LDS: 4 combos x (16KB rz + 8KB n) = 96KB
#define WBLK_BYTES   98304
#define COMBO_BYTES  24576
#define TL1_OFF      16384

typedef unsigned short ushort_t;
typedef uint32_t u32;
typedef unsigned long long u64;
typedef __attribute__((ext_vector_type(8))) short short8;
typedef __attribute__((ext_vector_type(4))) float f32x4;

union U4S8 { uint4 u; short8 s; };

// ---------- helpers ----------
__device__ __forceinline__ void unpack8(const uint4 v, float* f) {
  f[0] = __uint_as_float(v.x << 16);
  f[1] = __uint_as_float(v.x & 0xffff0000u);
  f[2] = __uint_as_float(v.y << 16);
  f[3] = __uint_as_float(v.y & 0xffff0000u);
  f[4] = __uint_as_float(v.z << 16);
  f[5] = __uint_as_float(v.z & 0xffff0000u);
  f[6] = __uint_as_float(v.w << 16);
  f[7] = __uint_as_float(v.w & 0xffff0000u);
}

__device__ __forceinline__ u32 f2bf_u(float x) {
  u32 u = __float_as_uint(x);
  return (u + 0x7fffu + ((u >> 16) & 1u)) >> 16;  // round-nearest-even
}
__device__ __forceinline__ ushort_t f2bf(float x) { return (ushort_t)f2bf_u(x); }

__device__ __forceinline__ float sigm(float x) { return 1.0f / (1.0f + expf(-x)); }

__device__ __forceinline__ void dot4(float& acc, const float* a, const float4 w) {
  acc = fmaf(a[0], w.x, acc);
  acc = fmaf(a[1], w.y, acc);
  acc = fmaf(a[2], w.z, acc);
  acc = fmaf(a[3], w.w, acc);
}

// ---------- coherence-point (sc1) access helpers ----------
__device__ __forceinline__ void st_sc32(u32* p, u32 v) {
  __hip_atomic_store(p, v, __ATOMIC_RELAXED, __HIP_MEMORY_SCOPE_AGENT);
}
__device__ __forceinline__ u32 ld_sc32(const u32* p) {
  return __hip_atomic_load((u32*)p, __ATOMIC_RELAXED, __HIP_MEMORY_SCOPE_AGENT);
}
// 16B coherence-point load (device-coherent, L2-bypass), issued without waitcnt;
// caller MUST drain with s_waitcnt vmcnt(0) + sched_barrier(0) before use.
__device__ __forceinline__ uint4 ld_sc128(const ushort_t* p) {
  uint4 r;
  asm volatile("global_load_dwordx4 %0, %1, off sc1" : "=v"(r) : "v"(p));
  return r;
}

// ---------- encoder ----------
__global__ __launch_bounds__(256) void enc_kernel(
    const float* __restrict__ x, const float* __restrict__ enc_w,
    const float* __restrict__ enc_b, ushort_t* __restrict__ enc_out)
{
  const int lane = threadIdx.x & 63;
  const int wv   = threadIdx.x >> 6;
  const int cb = blockIdx.x & 15;
  const int rb = blockIdx.x >> 4;
  const int j  = cb * 64 + lane;
  const int r0 = rb * 16 + wv * 4;
  const float* wrow = enc_w + (size_t)j * XDIM;
  const float* xr   = x + (size_t)r0 * XDIM;
  float acc[4] = {0.f, 0.f, 0.f, 0.f};
#pragma unroll
  for (int k = 0; k < XDIM; k += 4) {
    float4 w4 = *(const float4*)(wrow + k);
#pragma unroll
    for (int rr = 0; rr < 4; ++rr) {
      float4 xv = *(const float4*)(xr + rr * XDIM + k);
      acc[rr] = fmaf(xv.x, w4.x, acc[rr]);
      acc[rr] = fmaf(xv.y, w4.y, acc[rr]);
      acc[rr] = fmaf(xv.z, w4.z, acc[rr]);
      acc[rr] = fmaf(xv.w, w4.w, acc[rr]);
    }
  }
  float b = enc_b[j];
#pragma unroll
  for (int rr = 0; rr < 4; ++rr)
    enc_out[(size_t)(r0 + rr) * HDIM + j] = f2bf(tanhf(acc[rr] + b));
}

// ---------- weight pre-pack into per-block LDS image ----------
__global__ __launch_bounds__(256) void wprep_kernel(
    const float* __restrict__ w_ih, const float* __restrict__ w_hh,
    ushort_t* __restrict__ wfrag)
{
  const int lane = threadIdx.x & 63;
  const int wv   = threadIdx.x >> 6;
  const int c    = blockIdx.x * 4 + wv;
  const int ko = c & 15;
  const int tl = (c >> 4) & 1;
  const int c2 = (c >> 5) & 3;
  const int bid = c >> 7;
  const int g = c2 >> 1, kh = c2 & 1;
  const int layer = bid >> 7;
  const int j0 = (bid & 127) * 8;
  const float* wsrc = (g ? w_hh : w_ih) + (size_t)layer * 3 * HDIM * HDIM;

  if (tl == 0) {
    const int col = lane & 15, kgrp = lane >> 4;
    const int k = kh * 512 + ko * 32 + kgrp * 8;
    const int row = (col < 8) ? (j0 + col) : (HDIM + j0 + col - 8);
    const float* src = wsrc + (size_t)row * HDIM + k;
    short8 v;
#pragma unroll
    for (int e = 0; e < 8; ++e) v[e] = (short)f2bf(src[e]);
    const size_t byte = (size_t)bid * WBLK_BYTES + c2 * COMBO_BYTES + ko * 1024 + lane * 16;
    *(short8*)((char*)wfrag + byte) = v;
  } else if (lane < 32) {
    const int kgrp = lane >> 3, col = lane & 7;
    const int k = kh * 512 + ko * 32 + kgrp * 8;
    const int row = 2 * HDIM + j0 + col;
    const float* src = wsrc + (size_t)row * HDIM + k;
    short8 v;
#pragma unroll
    for (int e = 0; e < 8; ++e) v[e] = (short)f2bf(src[e]);
    const size_t byte = (size_t)bid * WBLK_BYTES + c2 * COMBO_BYTES + TL1_OFF + ko * 512 + lane * 16;
    *(short8*)((char*)wfrag + byte) = v;
  }
}

// ---------- per-group flag barrier (128 blocks) ----------
// Arrival: one sc1 store to own flag line. Leader block's threads 0..127 poll
// all flags, then publish monotone release. __syncthreads before arrival
// drains vmcnt so all data stores are at the coherence point first.
__device__ __forceinline__ void group_bar(u32* flags, u32* rel, int gbid,
                                          bool leader, u32 tag) {
  const int tid = threadIdx.x;
  __syncthreads();
  if (tid == 0) st_sc32(flags + (size_t)gbid * 64, tag);
  if (leader) {
    if (tid < 128) {
      u32* fp = flags + (size_t)tid * 64;
      while (ld_sc32(fp) < tag) __builtin_amdgcn_s_sleep(1);
    }
    __syncthreads();
    if (tid == 0) st_sc32(rel, tag);
  } else {
    if (tid == 0) {
      while (ld_sc32(rel) < tag) __builtin_amdgcn_s_sleep(1);
    }
    __syncthreads();
  }
}

// ---------- persistent recurrent kernel ----------
// L0 = blocks 0..127 (producer, runs ahead via 4-deep h0 ring);
// L1 = blocks 128..255 (consumer). Per-group barriers; cross-group waits are
// lagged release polls. Weights in LDS; fp32 h-state in registers.
__global__ __launch_bounds__(512, 1) void rnn_persist(
    const ushort_t* __restrict__ ench1,   // enc slices; slice t overwritten by h1(t)
    const ushort_t* __restrict__ wfrag,
    const float* __restrict__ b_ih, const float* __restrict__ b_hh,
    ushort_t* __restrict__ h0ring,        // 4 x [64][1024] bf16
    ushort_t* __restrict__ h1s,           // 2 x [64][1024] bf16
    ushort_t* __restrict__ h1_all,        // == ench1
    u32* __restrict__ l0_flags, u32* __restrict__ l1_flags,
    u32* __restrict__ l0_rel,   u32* __restrict__ l1_rel)
{
  extern __shared__ char smem[];          // 96KB weights + 32KB exchange = 128KB
  float* lds_part = (float*)(smem + WBLK_BYTES);

  const int tid  = threadIdx.x;
  const int lane = tid & 63;
  const int wid  = tid >> 6;
  const int bid  = blockIdx.x;
  const int layer = bid >> 7;
  const int j0    = (bid & 127) * 8;
  const int mp = wid & 1, g = (wid >> 1) & 1, kh = wid >> 2;
  const int col = lane & 15, kgrp = lane >> 4;
  const bool isL1 = (layer == 1);
  const int gbid = bid & 127;
  const bool leader = (gbid == 0);

  // ---- one-time: stage this block's 96KB weight image into LDS ----
  {
    const uint4* src = (const uint4*)((const char*)wfrag + (size_t)bid * WBLK_BYTES);
    uint4* dst = (uint4*)smem;
#pragma unroll 4
    for (int i = tid; i < WBLK_BYTES / 16; i += 512) dst[i] = src[i];
  }

  const int c2 = g * 2 + kh;
  const char* w0 = smem + c2 * COMBO_BYTES + lane * 16;
  const char* w1 = smem + c2 * COMBO_BYTES + TL1_OFF + (kgrp * 8 + (col & 7)) * 16;

  // ---- biases ----
  float bA = 0.f, bB = 0.f, bC = 0.f;
  {
    const float* bi = b_ih + layer * 3 * HDIM;
    const float* bh = b_hh + layer * 3 * HDIM;
    if (col < 8) {
      const int j = j0 + col;
      bA = bi[j] + bh[j];
      bB = bi[2 * HDIM + j];
      bC = bh[2 * HDIM + j];
    } else {
      const int j = j0 + col - 8;
      bA = bi[HDIM + j] + bh[HDIM + j];
    }
  }

  f32x4 hp = {0.f, 0.f, 0.f, 0.f};  // running fp32 h-state (waves 0-3, col<8)

  __syncthreads();  // LDS weight image ready

  for (int i = 0; i < T_STEPS; ++i) {
    // ---- cross-group waits ----
    if (isL1) {
      if (tid == 0) {  // need h0(i) complete
        while (ld_sc32(l0_rel) < (u32)(i + 1)) __builtin_amdgcn_s_sleep(1);
      }
    } else if (i >= 4) {
      if (tid == 0) {  // overwrite ring slot i&3: L1 must be done with step i-4
        while (ld_sc32(l1_rel) < (u32)(i - 3)) __builtin_amdgcn_s_sleep(1);
      }
    }
    __syncthreads();

    // ---- A operands ----
    const ushort_t* A1 = isL1 ? (h0ring + (size_t)(i & 3) * BH)
                              : (ench1 + (size_t)i * BH);
    const ushort_t* A2 = isL1 ? (h1s + (size_t)((i + 1) & 1) * BH)      // h1(i-1)
                              : (h0ring + (size_t)((i - 1) & 3) * BH);  // h0(i-1); i=0 -> slot 3 (zeros)
    const ushort_t* A = g ? A2 : A1;
    const bool coh = !(layer == 0 && g == 0);  // enc slices plain-cacheable

    const ushort_t* Arow0 = A + (size_t)(mp * 32 + col) * HDIM + kh * 512 + kgrp * 8;
    const ushort_t* Arow1 = Arow0 + 16 * HDIM;

    // ---- prefetch ALL A fragments into registers (wide, pipelined) ----
    uint4 areg[32];
    if (coh) {
#pragma unroll
      for (int ko = 0; ko < 16; ++ko) {
        areg[2 * ko]     = ld_sc128(Arow0 + ko * 32);
        areg[2 * ko + 1] = ld_sc128(Arow1 + ko * 32);
      }
    } else {
#pragma unroll
      for (int ko = 0; ko < 16; ++ko) {
        areg[2 * ko]     = *(const uint4*)(Arow0 + ko * 32);
        areg[2 * ko + 1] = *(const uint4*)(Arow1 + ko * 32);
      }
    }
    asm volatile("s_waitcnt vmcnt(0)" ::: "memory");
    __builtin_amdgcn_sched_barrier(0);

    // ---- MFMA over LDS-resident B fragments ----
    f32x4 acc00 = {0,0,0,0}, acc01 = {0,0,0,0}, acc10 = {0,0,0,0}, acc11 = {0,0,0,0};
#pragma unroll
    for (int ko = 0; ko < 16; ++ko) {
      const short8 b0 = *(const short8*)(w0 + ko * 1024);
      const short8 b1 = *(const short8*)(w1 + ko * 512);
      U4S8 ua0, ua1; ua0.u = areg[2 * ko]; ua1.u = areg[2 * ko + 1];
      acc00 = __builtin_amdgcn_mfma_f32_16x16x32_bf16(ua0.s, b0, acc00, 0, 0, 0);
      acc01 = __builtin_amdgcn_mfma_f32_16x16x32_bf16(ua0.s, b1, acc01, 0, 0, 0);
      acc10 = __builtin_amdgcn_mfma_f32_16x16x32_bf16(ua1.s, b0, acc10, 0, 0, 0);
      acc11 = __builtin_amdgcn_mfma_f32_16x16x32_bf16(ua1.s, b1, acc11, 0, 0, 0);
    }
    const int base = (wid * 4) * 256 + lane * 4;
    *(f32x4*)&lds_part[base      ] = acc00;
    *(f32x4*)&lds_part[base + 256] = acc01;
    *(f32x4*)&lds_part[base + 512] = acc10;
    *(f32x4*)&lds_part[base + 768] = acc11;

    __syncthreads();

    if (wid < 4) {
      const int m = wid, mpe = m >> 1, ime = m & 1;
      const int i00 = ((0 * 4 + 0 * 2 + mpe) * 4 + ime * 2);
      const int i01 = ((1 * 4 + 0 * 2 + mpe) * 4 + ime * 2);
      const int i10 = ((0 * 4 + 1 * 2 + mpe) * 4 + ime * 2);
      const int i11 = ((1 * 4 + 1 * 2 + mpe) * 4 + ime * 2);
      const int lo = lane * 4;
      f32x4 girz = *(f32x4*)&lds_part[i00 * 256 + lo] + *(f32x4*)&lds_part[i01 * 256 + lo];
      f32x4 gin  = *(f32x4*)&lds_part[(i00 + 1) * 256 + lo] + *(f32x4*)&lds_part[(i01 + 1) * 256 + lo];
      f32x4 ghrz = *(f32x4*)&lds_part[i10 * 256 + lo] + *(f32x4*)&lds_part[i11 * 256 + lo];
      f32x4 ghn  = *(f32x4*)&lds_part[(i10 + 1) * 256 + lo] + *(f32x4*)&lds_part[(i11 + 1) * 256 + lo];

      ushort_t* hdst = isL1 ? (h1s + (size_t)(i & 1) * BH)
                            : (h0ring + (size_t)(i & 3) * BH);
      ushort_t* hall = isL1 ? (h1_all + (size_t)i * BH) : (ushort_t*)0;

#pragma unroll
      for (int e = 0; e < 4; ++e) {
        const float rz = sigm(girz[e] + ghrz[e] + bA);
        const float nv = tanhf(gin[e] + bB + rz * (ghn[e] + bC));
        const float zv = __shfl_xor(rz, 8);
        const int b = m * 16 + kgrp * 4 + e;
        float h = 0.f;
        if (col < 8) {
          h = (1.f - zv) * nv + zv * hp[e];
          hp[e] = h;
        }
        const u32 hb = f2bf_u(h);
        const u32 pb = (u32)__shfl_xor((int)hb, 1);
        if (col < 8 && (col & 1) == 0) {
          const u32 pack = hb | (pb << 16);
          st_sc32((u32*)(hdst + b * HDIM + j0 + col), pack);
          if (hall) st_sc32((u32*)(hall + b * HDIM + j0 + col), pack);
        }
      }
    }

    // ---- own-group barrier ----
    if (isL1) group_bar(l1_flags, l1_rel, gbid, leader, (u32)(i + 1));
    else      group_bar(l0_flags, l0_rel, gbid, leader, (u32)(i + 1));
  }
}

// ---------- decoder ----------
__global__ __launch_bounds__(256) void dec_kernel(
    const ushort_t* __restrict__ h1_all, const float* __restrict__ dec_w,
    const float* __restrict__ dec_b, ushort_t* __restrict__ rnn_out)
{
  const int lane = threadIdx.x & 63;
  const int wv   = threadIdx.x >> 6;
  const int cb = blockIdx.x & 15;
  const int rb = blockIdx.x >> 4;
  const int row = rb * 64 + lane;
  const int j0  = cb * 64 + wv * 16;
  const ushort_t* a = h1_all + (size_t)row * HDIM;
  float acc[16];
#pragma unroll
  for (int c = 0; c < 16; ++c) acc[c] = 0.f;

#pragma unroll 1
  for (int k = 0; k < HDIM; k += 8) {
    float af[8];
    uint4 v = *(const uint4*)(a + k);
    unpack8(v, af);
#pragma unroll
    for (int c = 0; c < 16; ++c) {
      const float* wr = dec_w + (size_t)(j0 + c) * HDIM + k;
      dot4(acc[c], af,     *(const float4*)wr);
      dot4(acc[c], af + 4, *(const float4*)(wr + 4));
    }
  }
#pragma unroll
  for (int c = 0; c < 16; ++c) {
    float vq = tanhf(acc[c] + dec_b[j0 + c]);
    rnn_out[(size_t)row * HDIM + j0 + c] = f2bf(vq);
  }
}

// ---------- heads ----------
__global__ __launch_bounds__(256) void head_kernel(
    const ushort_t* __restrict__ rnn_out,
    const float* __restrict__ exp_w, const float* __restrict__ exp_b,
    const float* __restrict__ log_w, const float* __restrict__ log_b,
    float* __restrict__ outm, float* __restrict__ outv)
{
  const int lane = threadIdx.x & 63;
  const int wv   = threadIdx.x >> 6;
  const int row = blockIdx.x * 64 + lane;
  const int c0  = wv * 32;
  const ushort_t* a = rnn_out + (size_t)row * HDIM;
  const float* wmat = (c0 < 64) ? exp_w : log_w;
  const int cc0 = c0 & 63;

  float acc[32];
#pragma unroll
  for (int i = 0; i < 32; ++i) acc[i] = 0.f;

#pragma unroll 1
  for (int k = 0; k < HDIM; k += 8) {
    float af[8];
    uint4 v = *(const uint4*)(a + k);
    unpack8(v, af);
#pragma unroll
    for (int i = 0; i < 32; ++i) {
      const float* wr = wmat + (size_t)(cc0 + i) * HDIM + k;
      dot4(acc[i], af,     *(const float4*)wr);
      dot4(acc[i], af + 4, *(const float4*)(wr + 4));
    }
  }

  if (c0 < 64) {
#pragma unroll
    for (int i = 0; i < 32; ++i) {
      int y = cc0 + i;
      outm[(size_t)row * YDIM + y] = acc[i] + exp_b[y];
    }
  } else {
#pragma unroll
    for (int i = 0; i < 32; ++i) {
      int y = cc0 + i;
      outv[(size_t)row * YDIM + y] = expf(acc[i] + log_b[y]);
    }
  }
}

// ---------- host ----------
extern "C" void kernel_launch(void* const* d_in, const int* in_sizes, int n_in,
                              void* d_out, int out_size, void* d_ws, size_t ws_size,
                              hipStream_t stream) {
  (void)in_sizes; (void)n_in; (void)out_size; (void)ws_size;
  const float* x     = (const float*)d_in[0];
  const float* enc_w = (const float*)d_in[1];
  const float* enc_b = (const float*)d_in[2];
  const float* w_ih  = (const float*)d_in[3];
  const float* w_hh  = (const float*)d_in[4];
  const float* b_ih  = (const float*)d_in[5];
  const float* b_hh  = (const float*)d_in[6];
  const float* dec_w = (const float*)d_in[7];
  const float* dec_b = (const float*)d_in[8];
  const float* exp_w = (const float*)d_in[9];
  const float* exp_b = (const float*)d_in[10];
  const float* log_w = (const float*)d_in[11];
  const float* log_b = (const float*)d_in[12];
  float* out = (float*)d_out;

  char* ws = (char*)d_ws;
  ushort_t* h1s     = (ushort_t*)ws;                        // 2 x 128KB = 256 KB
  ushort_t* h0ring  = (ushort_t*)(ws + 262144);             // 4 x 128KB = 512 KB
  u32*      l0f     = (u32*)(ws + 786432);                  // 128 x 256B = 32 KB
  u32*      l1f     = (u32*)(ws + 819200);                  // 32 KB
  u32*      l0r     = (u32*)(ws + 851968);                  // own line
  u32*      l1r     = (u32*)(ws + 852224);                  // own line
  ushort_t* wfrag   = (ushort_t*)(ws + 2097152);            // 24 MB (reused as staging)
  ushort_t* ench1   = (ushort_t*)(ws + 2097152 + 33554432); // 64 MB enc slices / h1_all

  hipMemsetAsync(ws, 0, 860160, stream);  // h-states + ring + flags + releases

  enc_kernel<<<32768, 256, 0, stream>>>(x, enc_w, enc_b, ench1);
  wprep_kernel<<<8192, 256, 0, stream>>>(w_ih, w_hh, wfrag);

  {
    static int lds_opted = 0;
    if (!lds_opted) {
      hipFuncSetAttribute((const void*)rnn_persist,
                          hipFuncAttributeMaxDynamicSharedMemorySize, 131072);
      lds_opted = 1;
    }
    void* args[11];
    args[0]  = (void*)&ench1;
    args[1]  = (void*)&wfrag;
    args[2]  = (void*)&b_ih;
    args[3]  = (void*)&b_hh;
    args[4]  = (void*)&h0ring;
    args[5]  = (void*)&h1s;
    args[6]  = (void*)&ench1;
    args[7]  = (void*)&l0f;
    args[8]  = (void*)&l1f;
    args[9]  = (void*)&l0r;
    args[10] = (void*)&l1r;
    hipLaunchCooperativeKernel((const void*)rnn_persist, dim3(256), dim3(512),
                               args, 131072, stream);
  }

  ushort_t* staging = wfrag;
  for (int half = 0; half < 2; ++half) {
    const ushort_t* h1p = ench1 + (size_t)half * 16384 * HDIM;
    dec_kernel<<<4096, 256, 0, stream>>>(h1p, dec_w, dec_b, staging);
    float* outm = out + (size_t)half * 16384 * YDIM;
    float* outv = out + (size_t)T_STEPS * BATCH * YDIM + (size_t)half * 16384 * YDIM;
    head_kernel<<<256, 256, 0, stream>>>(staging, exp_w, exp_b, log_w, log_b, outm, outv);
  }
}

// Round 9
// 5984.415 us; speedup vs baseline: 2.9032x; 1.8339x over previous
//
#include <hip/hip_runtime.h>
#include <hip/hip_bf16.h>
#include <cstdint>

#define T_STEPS 512
#define BATCH   64
#define XDIM    64
#define HDIM    1024
#define YDIM    64
#define BH      (BATCH * HDIM)
#define RING_D  32

// per-block weight slice in LDS: 4 combos x (16KB rz + 8KB n) = 96KB
#define WBLK_BYTES   98304
#define COMBO_BYTES  24576
#define TL1_OFF      16384

typedef unsigned short ushort_t;
typedef uint32_t u32;
typedef unsigned long long u64;
typedef __attribute__((ext_vector_type(8))) short short8;
typedef __attribute__((ext_vector_type(4))) float f32x4;

// ---------- helpers ----------
__device__ __forceinline__ u32 f2bf_u(float x) {
  u32 u = __float_as_uint(x);
  return (u + 0x7fffu + ((u >> 16) & 1u)) >> 16;  // round-nearest-even
}
__device__ __forceinline__ ushort_t f2bf(float x) { return (ushort_t)f2bf_u(x); }

__device__ __forceinline__ float sigm(float x) { return 1.0f / (1.0f + expf(-x)); }

// ---------- coherence-point (sc1) access helpers (stores/flags only) ----------
__device__ __forceinline__ void st_sc32(u32* p, u32 v) {
  __hip_atomic_store(p, v, __ATOMIC_RELAXED, __HIP_MEMORY_SCOPE_AGENT);
}
__device__ __forceinline__ u32 ld_sc32(const u32* p) {
  return __hip_atomic_load((u32*)p, __ATOMIC_RELAXED, __HIP_MEMORY_SCOPE_AGENT);
}

// ---------- encoder: LDS-staged weights (coalesced), bf16 out ----------
__global__ __launch_bounds__(256) void enc_kernel(
    const float* __restrict__ x, const float* __restrict__ enc_w,
    const float* __restrict__ enc_b, ushort_t* __restrict__ enc_out)
{
  __shared__ float wlds[64 * 65];  // stride 65: conflict-free lane*65+k reads
  const int lane = threadIdx.x & 63;
  const int wv   = threadIdx.x >> 6;
  const int cb = blockIdx.x & 15;
  const int rb = blockIdx.x >> 4;
  const int j  = cb * 64 + lane;
  const int r0 = rb * 16 + wv * 4;

  // stage enc_w rows [cb*64 .. +63] (contiguous 16KB) coalesced
  const float* wsrc = enc_w + (size_t)cb * 64 * XDIM;
  for (int i = threadIdx.x; i < 4096; i += 256)
    wlds[(i >> 6) * 65 + (i & 63)] = wsrc[i];
  __syncthreads();

  const float* xr = x + (size_t)r0 * XDIM;
  float acc[4] = {0.f, 0.f, 0.f, 0.f};
#pragma unroll
  for (int k = 0; k < XDIM; k += 4) {
    const float w0 = wlds[lane * 65 + k];
    const float w1 = wlds[lane * 65 + k + 1];
    const float w2 = wlds[lane * 65 + k + 2];
    const float w3 = wlds[lane * 65 + k + 3];
#pragma unroll
    for (int rr = 0; rr < 4; ++rr) {
      const float* xp = xr + rr * XDIM + k;  // wave-uniform
      acc[rr] = fmaf(xp[3], w3, fmaf(xp[2], w2, fmaf(xp[1], w1, fmaf(xp[0], w0, acc[rr]))));
    }
  }
  const float b = enc_b[j];
#pragma unroll
  for (int rr = 0; rr < 4; ++rr)
    enc_out[(size_t)(r0 + rr) * HDIM + j] = f2bf(tanhf(acc[rr] + b));
}

// ---------- GRU weight pre-pack into per-block LDS image ----------
__global__ __launch_bounds__(256) void wprep_kernel(
    const float* __restrict__ w_ih, const float* __restrict__ w_hh,
    ushort_t* __restrict__ wfrag)
{
  const int lane = threadIdx.x & 63;
  const int wv   = threadIdx.x >> 6;
  const int c    = blockIdx.x * 4 + wv;
  const int ko = c & 15;
  const int tl = (c >> 4) & 1;
  const int c2 = (c >> 5) & 3;
  const int bid = c >> 7;
  const int g = c2 >> 1, kh = c2 & 1;
  const int layer = bid >> 7;
  const int j0 = (bid & 127) * 8;
  const float* wsrc = (g ? w_hh : w_ih) + (size_t)layer * 3 * HDIM * HDIM;

  if (tl == 0) {
    const int col = lane & 15, kgrp = lane >> 4;
    const int k = kh * 512 + ko * 32 + kgrp * 8;
    const int row = (col < 8) ? (j0 + col) : (HDIM + j0 + col - 8);
    const float* src = wsrc + (size_t)row * HDIM + k;
    short8 v;
#pragma unroll
    for (int e = 0; e < 8; ++e) v[e] = (short)f2bf(src[e]);
    const size_t byte = (size_t)bid * WBLK_BYTES + c2 * COMBO_BYTES + ko * 1024 + lane * 16;
    *(short8*)((char*)wfrag + byte) = v;
  } else if (lane < 32) {
    const int kgrp = lane >> 3, col = lane & 7;
    const int k = kh * 512 + ko * 32 + kgrp * 8;
    const int row = 2 * HDIM + j0 + col;
    const float* src = wsrc + (size_t)row * HDIM + k;
    short8 v;
#pragma unroll
    for (int e = 0; e < 8; ++e) v[e] = (short)f2bf(src[e]);
    const size_t byte = (size_t)bid * WBLK_BYTES + c2 * COMBO_BYTES + TL1_OFF + ko * 512 + lane * 16;
    *(short8*)((char*)wfrag + byte) = v;
  }
}

// ---------- dec/head weight frag pre-pack (bf16, MFMA B-frag order) ----------
// dec: 64 nt x 32 kc chunks; head: 8 nt x 32 kc. chunk = 64 lanes x 16B.
__global__ __launch_bounds__(256) void wprep2_kernel(
    const float* __restrict__ dec_w, const float* __restrict__ exp_w,
    const float* __restrict__ log_w,
    ushort_t* __restrict__ dwfrag, ushort_t* __restrict__ hwfrag)
{
  const int lane = threadIdx.x & 63;
  const int wv   = threadIdx.x >> 6;
  const int c    = blockIdx.x * 4 + wv;   // 0..2303
  short8 v;
  if (c < 2048) {
    const int nt = c >> 5, kc = c & 31;
    const int row = nt * 16 + (lane & 15);
    const int k   = kc * 32 + (lane >> 4) * 8;
    const float* src = dec_w + (size_t)row * HDIM + k;
#pragma unroll
    for (int e = 0; e < 8; ++e) v[e] = (short)f2bf(src[e]);
    *(short8*)(dwfrag + (size_t)c * 512 + lane * 8) = v;
  } else {
    const int c2 = c - 2048;
    const int nt = c2 >> 5, kc = c2 & 31;
    const int row = nt * 16 + (lane & 15);     // 0..127
    const int k   = kc * 32 + (lane >> 4) * 8;
    const float* src = (row < 64) ? (exp_w + (size_t)row * HDIM + k)
                                  : (log_w + (size_t)(row - 64) * HDIM + k);
#pragma unroll
    for (int e = 0; e < 8; ++e) v[e] = (short)f2bf(src[e]);
    *(short8*)(hwfrag + (size_t)c2 * 512 + lane * 8) = v;
  }
}

// ---------- per-group flag barrier (128 blocks) ----------
__device__ __forceinline__ void group_bar(u32* flags, u32* rel, int gbid,
                                          bool leader, u32 tag) {
  const int tid = threadIdx.x;
  __syncthreads();
  if (tid == 0) st_sc32(flags + (size_t)gbid * 64, tag);
  if (leader) {
    if (tid < 128) {
      u32* fp = flags + (size_t)tid * 64;
      while (ld_sc32(fp) < tag) __builtin_amdgcn_s_sleep(1);
    }
    __syncthreads();
    if (tid == 0) st_sc32(rel, tag);
  } else {
    if (tid == 0) {
      while (ld_sc32(rel) < tag) __builtin_amdgcn_s_sleep(1);
    }
    __syncthreads();
  }
}

// ---------- persistent recurrent kernel ----------
// L0 = blocks 0..127 (producer into 32-deep h0 ring); L1 = blocks 128..255.
// Bulk A-reads: PLAIN cached loads (streaming/first-touch addresses).
// h stores: sc1 (straight to L3) + flag barriers for visibility.
__global__ __launch_bounds__(512, 1) void rnn_persist(
    const ushort_t* __restrict__ ench1,
    const ushort_t* __restrict__ wfrag,
    const float* __restrict__ b_ih, const float* __restrict__ b_hh,
    ushort_t* __restrict__ h0ring,        // 32 x [64][1024] bf16
    ushort_t* __restrict__ h1ring,        // 32 x [64][1024] bf16
    ushort_t* __restrict__ h1_all,        // 512 slices for dechead
    u32* __restrict__ l0_flags, u32* __restrict__ l1_flags,
    u32* __restrict__ l0_rel,   u32* __restrict__ l1_rel)
{
  extern __shared__ char smem[];          // 96KB weights + 32KB exchange
  float* lds_part = (float*)(smem + WBLK_BYTES);

  const int tid  = threadIdx.x;
  const int lane = tid & 63;
  const int wid  = tid >> 6;
  const int bid  = blockIdx.x;
  const int layer = bid >> 7;
  const int j0    = (bid & 127) * 8;
  const int mp = wid & 1, g = (wid >> 1) & 1, kh = wid >> 2;
  const int col = lane & 15, kgrp = lane >> 4;
  const bool isL1 = (layer == 1);
  const int gbid = bid & 127;
  const bool leader = (gbid == 0);

  // ---- one-time: stage this block's 96KB weight image into LDS ----
  {
    const uint4* src = (const uint4*)((const char*)wfrag + (size_t)bid * WBLK_BYTES);
    uint4* dst = (uint4*)smem;
#pragma unroll 4
    for (int i = tid; i < WBLK_BYTES / 16; i += 512) dst[i] = src[i];
  }

  const int c2 = g * 2 + kh;
  const char* w0 = smem + c2 * COMBO_BYTES + lane * 16;
  const char* w1 = smem + c2 * COMBO_BYTES + TL1_OFF + (kgrp * 8 + (col & 7)) * 16;

  // ---- biases ----
  float bA = 0.f, bB = 0.f, bC = 0.f;
  {
    const float* bi = b_ih + layer * 3 * HDIM;
    const float* bh = b_hh + layer * 3 * HDIM;
    if (col < 8) {
      const int j = j0 + col;
      bA = bi[j] + bh[j];
      bB = bi[2 * HDIM + j];
      bC = bh[2 * HDIM + j];
    } else {
      const int j = j0 + col - 8;
      bA = bi[HDIM + j] + bh[HDIM + j];
    }
  }

  f32x4 hp = {0.f, 0.f, 0.f, 0.f};  // running fp32 h-state (waves 0-3, col<8)

  __syncthreads();  // LDS weight image ready

  for (int i = 0; i < T_STEPS; ++i) {
    // ---- cross-group waits ----
    if (isL1) {
      if (tid == 0) {  // need h0(i) complete
        while (ld_sc32(l0_rel) < (u32)(i + 1)) __builtin_amdgcn_s_sleep(1);
      }
    } else if (i >= RING_D) {
      if (tid == 0) {  // overwrite slot i&31 (holds h0[i-32]): L1 done with i-32
        while (ld_sc32(l1_rel) < (u32)(i - RING_D + 1)) __builtin_amdgcn_s_sleep(1);
      }
    }
    __syncthreads();

    const ushort_t* A1 = isL1 ? (h0ring + (size_t)(i & (RING_D - 1)) * BH)
                              : (ench1 + (size_t)i * BH);
    const ushort_t* A2 = isL1 ? (h1ring + (size_t)((i - 1) & (RING_D - 1)) * BH)
                              : (h0ring + (size_t)((i - 1) & (RING_D - 1)) * BH);
    const ushort_t* A = g ? A2 : A1;
    const ushort_t* Arow0 = A + (size_t)(mp * 32 + col) * HDIM + kh * 512 + kgrp * 8;
    const ushort_t* Arow1 = Arow0 + 16 * HDIM;

    f32x4 acc00 = {0,0,0,0}, acc01 = {0,0,0,0}, acc10 = {0,0,0,0}, acc11 = {0,0,0,0};
#pragma unroll
    for (int ko = 0; ko < 16; ++ko) {
      const short8 a0 = *(const short8*)(Arow0 + ko * 32);
      const short8 a1 = *(const short8*)(Arow1 + ko * 32);
      const short8 b0 = *(const short8*)(w0 + ko * 1024);
      const short8 b1 = *(const short8*)(w1 + ko * 512);
      acc00 = __builtin_amdgcn_mfma_f32_16x16x32_bf16(a0, b0, acc00, 0, 0, 0);
      acc01 = __builtin_amdgcn_mfma_f32_16x16x32_bf16(a0, b1, acc01, 0, 0, 0);
      acc10 = __builtin_amdgcn_mfma_f32_16x16x32_bf16(a1, b0, acc10, 0, 0, 0);
      acc11 = __builtin_amdgcn_mfma_f32_16x16x32_bf16(a1, b1, acc11, 0, 0, 0);
    }
    const int base = (wid * 4) * 256 + lane * 4;
    *(f32x4*)&lds_part[base      ] = acc00;
    *(f32x4*)&lds_part[base + 256] = acc01;
    *(f32x4*)&lds_part[base + 512] = acc10;
    *(f32x4*)&lds_part[base + 768] = acc11;

    __syncthreads();

    if (wid < 4) {
      const int m = wid, mpe = m >> 1, ime = m & 1;
      const int i00 = ((0 * 4 + 0 * 2 + mpe) * 4 + ime * 2);
      const int i01 = ((1 * 4 + 0 * 2 + mpe) * 4 + ime * 2);
      const int i10 = ((0 * 4 + 1 * 2 + mpe) * 4 + ime * 2);
      const int i11 = ((1 * 4 + 1 * 2 + mpe) * 4 + ime * 2);
      const int lo = lane * 4;
      f32x4 girz = *(f32x4*)&lds_part[i00 * 256 + lo] + *(f32x4*)&lds_part[i01 * 256 + lo];
      f32x4 gin  = *(f32x4*)&lds_part[(i00 + 1) * 256 + lo] + *(f32x4*)&lds_part[(i01 + 1) * 256 + lo];
      f32x4 ghrz = *(f32x4*)&lds_part[i10 * 256 + lo] + *(f32x4*)&lds_part[i11 * 256 + lo];
      f32x4 ghn  = *(f32x4*)&lds_part[(i10 + 1) * 256 + lo] + *(f32x4*)&lds_part[(i11 + 1) * 256 + lo];

      ushort_t* hdst = isL1 ? (h1ring + (size_t)(i & (RING_D - 1)) * BH)
                            : (h0ring + (size_t)(i & (RING_D - 1)) * BH);
      ushort_t* hall = isL1 ? (h1_all + (size_t)i * BH) : (ushort_t*)0;

#pragma unroll
      for (int e = 0; e < 4; ++e) {
        const float rz = sigm(girz[e] + ghrz[e] + bA);
        const float nv = tanhf(gin[e] + bB + rz * (ghn[e] + bC));
        const float zv = __shfl_xor(rz, 8);
        const int b = m * 16 + kgrp * 4 + e;
        float h = 0.f;
        if (col < 8) {
          h = (1.f - zv) * nv + zv * hp[e];
          hp[e] = h;
        }
        const u32 hb = f2bf_u(h);
        const u32 pb = (u32)__shfl_xor((int)hb, 1);
        if (col < 8 && (col & 1) == 0) {
          const u32 pack = hb | (pb << 16);
          st_sc32((u32*)(hdst + b * HDIM + j0 + col), pack);
          if (hall) st_sc32((u32*)(hall + b * HDIM + j0 + col), pack);
        }
      }
    }

    if (isL1) group_bar(l1_flags, l1_rel, gbid, leader, (u32)(i + 1));
    else      group_bar(l0_flags, l0_rel, gbid, leader, (u32)(i + 1));
  }
}

// ---------- fused decoder + heads (bf16 MFMA) ----------
// Block: 32 rows, 512 thr (8 waves). Phase1: rnn_out tile = tanh(h1@dec_w.T+b)
// into LDS. Phase2: heads from LDS. A-tile stride 1032 elems (16B-aligned, low conflict).
#define AST 1032
__global__ __launch_bounds__(512, 1) void dechead_kernel(
    const ushort_t* __restrict__ h1_all,
    const ushort_t* __restrict__ dwfrag, const ushort_t* __restrict__ hwfrag,
    const float* __restrict__ dec_b, const float* __restrict__ exp_b,
    const float* __restrict__ log_b, float* __restrict__ out)
{
  extern __shared__ char smem2[];
  ushort_t* Alds = (ushort_t*)smem2;             // [32][AST]
  ushort_t* Rlds = Alds + 32 * AST;              // [32][AST]

  const int tid  = threadIdx.x;
  const int lane = tid & 63;
  const int wv   = tid >> 6;
  const int base = blockIdx.x * 32;

  // ---- stage A tile (32 rows x 1024 bf16, contiguous 64KB) coalesced ----
  {
    const uint4* src = (const uint4*)(h1_all + (size_t)base * HDIM);
#pragma unroll
    for (int ii = 0; ii < 8; ++ii) {
      const int idx = ii * 512 + tid;          // uint4 index, 4096 total
      const int row = idx >> 7;                // 128 uint4 per row
      const int k   = (idx & 127) * 8;
      *(uint4*)(Alds + row * AST + k) = src[idx];
    }
  }
  __syncthreads();

  // ---- phase 1: dec GEMM, wave wv owns cols [wv*128 .. +127] ----
  f32x4 acc[8][2];
#pragma unroll
  for (int t = 0; t < 8; ++t) { acc[t][0] = (f32x4){0,0,0,0}; acc[t][1] = (f32x4){0,0,0,0}; }

  const int r0 = lane & 15, kg = lane >> 4;
  const int nt0 = wv * 8;
#pragma unroll 1
  for (int t = 0; t < 8; ++t) {
    const ushort_t* bsrc = dwfrag + (size_t)(nt0 + t) * 32 * 512 + lane * 8;
    f32x4 c0 = acc[t][0], c1 = acc[t][1];
#pragma unroll
    for (int kc = 0; kc < 32; ++kc) {
      const short8 b  = *(const short8*)(bsrc + kc * 512);
      const short8 a0 = *(const short8*)(Alds + r0 * AST + kc * 32 + kg * 8);
      const short8 a1 = *(const short8*)(Alds + (16 + r0) * AST + kc * 32 + kg * 8);
      c0 = __builtin_amdgcn_mfma_f32_16x16x32_bf16(a0, b, c0, 0, 0, 0);
      c1 = __builtin_amdgcn_mfma_f32_16x16x32_bf16(a1, b, c1, 0, 0, 0);
    }
    acc[t][0] = c0; acc[t][1] = c1;
  }

  // epilogue 1: tanh + bias -> Rlds (bf16)
#pragma unroll
  for (int t = 0; t < 8; ++t) {
    const int colc = (nt0 + t) * 16 + r0;
    const float db = dec_b[colc];
#pragma unroll
    for (int m = 0; m < 2; ++m) {
      const f32x4 v = acc[t][m];
#pragma unroll
      for (int e = 0; e < 4; ++e) {
        const int row = m * 16 + kg * 4 + e;
        Rlds[row * AST + colc] = (ushort_t)f2bf_u(tanhf(v[e] + db));
      }
    }
  }
  __syncthreads();

  // ---- phase 2: heads, wave wv owns output cols [wv*16 .. +15] of 128 ----
  f32x4 h0a = {0,0,0,0}, h1a = {0,0,0,0};
  {
    const ushort_t* bsrc = hwfrag + (size_t)wv * 32 * 512 + lane * 8;
#pragma unroll
    for (int kc = 0; kc < 32; ++kc) {
      const short8 b  = *(const short8*)(bsrc + kc * 512);
      const short8 a0 = *(const short8*)(Rlds + r0 * AST + kc * 32 + kg * 8);
      const short8 a1 = *(const short8*)(Rlds + (16 + r0) * AST + kc * 32 + kg * 8);
      h0a = __builtin_amdgcn_mfma_f32_16x16x32_bf16(a0, b, h0a, 0, 0, 0);
      h1a = __builtin_amdgcn_mfma_f32_16x16x32_bf16(a1, b, h1a, 0, 0, 0);
    }
  }
  const int y = wv * 16 + r0;  // 0..127
  if (wv < 4) {
    const float eb = exp_b[y];
#pragma unroll
    for (int m = 0; m < 2; ++m) {
      const f32x4 v = (m == 0) ? h0a : h1a;
#pragma unroll
      for (int e = 0; e < 4; ++e) {
        const int row = m * 16 + kg * 4 + e;
        out[(size_t)(base + row) * YDIM + y] = v[e] + eb;
      }
    }
  } else {
    const int yv = y - 64;
    const float lb = log_b[yv];
#pragma unroll
    for (int m = 0; m < 2; ++m) {
      const f32x4 v = (m == 0) ? h0a : h1a;
#pragma unroll
      for (int e = 0; e < 4; ++e) {
        const int row = m * 16 + kg * 4 + e;
        out[(size_t)(T_STEPS * BATCH * YDIM) + (size_t)(base + row) * YDIM + yv] = expf(v[e] + lb);
      }
    }
  }
}

// ---------- host ----------
extern "C" void kernel_launch(void* const* d_in, const int* in_sizes, int n_in,
                              void* d_out, int out_size, void* d_ws, size_t ws_size,
                              hipStream_t stream) {
  (void)in_sizes; (void)n_in; (void)out_size; (void)ws_size;
  const float* x     = (const float*)d_in[0];
  const float* enc_w = (const float*)d_in[1];
  const float* enc_b = (const float*)d_in[2];
  const float* w_ih  = (const float*)d_in[3];
  const float* w_hh  = (const float*)d_in[4];
  const float* b_ih  = (const float*)d_in[5];
  const float* b_hh  = (const float*)d_in[6];
  const float* dec_w = (const float*)d_in[7];
  const float* dec_b = (const float*)d_in[8];
  const float* exp_w = (const float*)d_in[9];
  const float* exp_b = (const float*)d_in[10];
  const float* log_w = (const float*)d_in[11];
  const float* log_b = (const float*)d_in[12];
  float* out = (float*)d_out;

  char* ws = (char*)d_ws;
  u32*      l0f     = (u32*)ws;                             // 32 KB
  u32*      l1f     = (u32*)(ws + 32768);                   // 32 KB
  u32*      l0r     = (u32*)(ws + 65536);
  u32*      l1r     = (u32*)(ws + 65792);
  ushort_t* wfrag   = (ushort_t*)(ws + 2097152);            // 24 MB
  ushort_t* h0ring  = (ushort_t*)(ws + 27262976);           // 4 MB (32 slots)
  ushort_t* h1ring  = (ushort_t*)(ws + 31457280);           // 4 MB
  ushort_t* ench1   = (ushort_t*)(ws + 35651584);           // 64 MB enc slices / h1_all
  ushort_t* dwfrag  = (ushort_t*)(ws + 102760448);          // 2 MB
  ushort_t* hwfrag  = (ushort_t*)(ws + 104857600);          // 256 KB

  hipMemsetAsync(ws, 0, 66048, stream);                     // flags + releases
  hipMemsetAsync(ws + 27262976, 0, 8388608, stream);        // both rings

  enc_kernel<<<32768, 256, 0, stream>>>(x, enc_w, enc_b, ench1);
  wprep_kernel<<<8192, 256, 0, stream>>>(w_ih, w_hh, wfrag);
  wprep2_kernel<<<576, 256, 0, stream>>>(dec_w, exp_w, log_w, dwfrag, hwfrag);

  {
    static int lds_opted = 0;
    if (!lds_opted) {
      hipFuncSetAttribute((const void*)rnn_persist,
                          hipFuncAttributeMaxDynamicSharedMemorySize, 131072);
      hipFuncSetAttribute((const void*)dechead_kernel,
                          hipFuncAttributeMaxDynamicSharedMemorySize, 2 * 32 * AST * 2);
      lds_opted = 1;
    }
    void* args[11];
    args[0]  = (void*)&ench1;
    args[1]  = (void*)&wfrag;
    args[2]  = (void*)&b_ih;
    args[3]  = (void*)&b_hh;
    args[4]  = (void*)&h0ring;
    args[5]  = (void*)&h1ring;
    args[6]  = (void*)&ench1;
    args[7]  = (void*)&l0f;
    args[8]  = (void*)&l1f;
    args[9]  = (void*)&l0r;
    args[10] = (void*)&l1r;
    hipLaunchCooperativeKernel((const void*)rnn_persist, dim3(256), dim3(512),
                               args, 131072, stream);
  }

  dechead_kernel<<<1024, 512, 2 * 32 * AST * 2, stream>>>(
      ench1, dwfrag, hwfrag, dec_b, exp_b, log_b, out);
}

// Round 10
// 5573.094 us; speedup vs baseline: 3.1175x; 1.0738x over previous
//
#include <hip/hip_runtime.h>
#include <hip/hip_bf16.h>
#include <cstdint>

#define T_STEPS 512
#define BATCH   64
#define XDIM    64
#define HDIM    1024
#define YDIM    64
#define BH      (BATCH * HDIM)
#define RING_D  32

// per-block weight slice in LDS: 4 combos x (16KB rz + 8KB n) = 96KB
#define WBLK_BYTES   98304
#define COMBO_BYTES  24576
#define TL1_OFF      16384

typedef unsigned short ushort_t;
typedef uint32_t u32;
typedef unsigned long long u64;
typedef __attribute__((ext_vector_type(8))) short short8;
typedef __attribute__((ext_vector_type(4))) float f32x4;

union U4S8 { uint4 u; short8 s; };

// ---------- helpers ----------
__device__ __forceinline__ u32 f2bf_u(float x) {
  u32 u = __float_as_uint(x);
  return (u + 0x7fffu + ((u >> 16) & 1u)) >> 16;  // round-nearest-even
}
__device__ __forceinline__ ushort_t f2bf(float x) { return (ushort_t)f2bf_u(x); }

__device__ __forceinline__ float sigm(float x) { return 1.0f / (1.0f + expf(-x)); }

// ---------- coherence-point (sc1) helpers for flags ----------
__device__ __forceinline__ void st_sc32(u32* p, u32 v) {
  __hip_atomic_store(p, v, __ATOMIC_RELAXED, __HIP_MEMORY_SCOPE_AGENT);
}

// plain cached 16B load, issue-ordered (asm volatile)
__device__ __forceinline__ uint4 ld_g128(const ushort_t* p) {
  uint4 r;
  asm volatile("global_load_dwordx4 %0, %1, off" : "=v"(r) : "v"(p));
  return r;
}

// one 16B sc1 flag read + drain; returns all-4 >= tag
__device__ __forceinline__ int flags_ok(const u32* p, u32 tag) {
  uint4 f;
  asm volatile("global_load_dwordx4 %0, %1, off sc1\n\ts_waitcnt vmcnt(0)"
               : "=v"(f) : "v"(p) : "memory");
  return (f.x >= tag) && (f.y >= tag) && (f.z >= tag) && (f.w >= tag);
}
// thread t (0..31) guards flags[4t..4t+3]
__device__ __forceinline__ void poll4(const u32* flags, int t, u32 tag) {
  const u32* p = flags + 4 * t;
  while (!flags_ok(p, tag)) __builtin_amdgcn_s_sleep(1);
}

// ---------- encoder: LDS-staged weights (coalesced), bf16 out ----------
__global__ __launch_bounds__(256) void enc_kernel(
    const float* __restrict__ x, const float* __restrict__ enc_w,
    const float* __restrict__ enc_b, ushort_t* __restrict__ enc_out)
{
  __shared__ float wlds[64 * 65];
  const int lane = threadIdx.x & 63;
  const int wv   = threadIdx.x >> 6;
  const int cb = blockIdx.x & 15;
  const int rb = blockIdx.x >> 4;
  const int j  = cb * 64 + lane;
  const int r0 = rb * 16 + wv * 4;

  const float* wsrc = enc_w + (size_t)cb * 64 * XDIM;
  for (int i = threadIdx.x; i < 4096; i += 256)
    wlds[(i >> 6) * 65 + (i & 63)] = wsrc[i];
  __syncthreads();

  const float* xr = x + (size_t)r0 * XDIM;
  float acc[4] = {0.f, 0.f, 0.f, 0.f};
#pragma unroll
  for (int k = 0; k < XDIM; k += 4) {
    const float w0 = wlds[lane * 65 + k];
    const float w1 = wlds[lane * 65 + k + 1];
    const float w2 = wlds[lane * 65 + k + 2];
    const float w3 = wlds[lane * 65 + k + 3];
#pragma unroll
    for (int rr = 0; rr < 4; ++rr) {
      const float* xp = xr + rr * XDIM + k;
      acc[rr] = fmaf(xp[3], w3, fmaf(xp[2], w2, fmaf(xp[1], w1, fmaf(xp[0], w0, acc[rr]))));
    }
  }
  const float b = enc_b[j];
#pragma unroll
  for (int rr = 0; rr < 4; ++rr)
    enc_out[(size_t)(r0 + rr) * HDIM + j] = f2bf(tanhf(acc[rr] + b));
}

// ---------- GRU weight pre-pack into per-block LDS image ----------
__global__ __launch_bounds__(256) void wprep_kernel(
    const float* __restrict__ w_ih, const float* __restrict__ w_hh,
    ushort_t* __restrict__ wfrag)
{
  const int lane = threadIdx.x & 63;
  const int wv   = threadIdx.x >> 6;
  const int c    = blockIdx.x * 4 + wv;
  const int ko = c & 15;
  const int tl = (c >> 4) & 1;
  const int c2 = (c >> 5) & 3;
  const int bid = c >> 7;
  const int g = c2 >> 1, kh = c2 & 1;
  const int layer = bid >> 7;
  const int j0 = (bid & 127) * 8;
  const float* wsrc = (g ? w_hh : w_ih) + (size_t)layer * 3 * HDIM * HDIM;

  if (tl == 0) {
    const int col = lane & 15, kgrp = lane >> 4;
    const int k = kh * 512 + ko * 32 + kgrp * 8;
    const int row = (col < 8) ? (j0 + col) : (HDIM + j0 + col - 8);
    const float* src = wsrc + (size_t)row * HDIM + k;
    short8 v;
#pragma unroll
    for (int e = 0; e < 8; ++e) v[e] = (short)f2bf(src[e]);
    const size_t byte = (size_t)bid * WBLK_BYTES + c2 * COMBO_BYTES + ko * 1024 + lane * 16;
    *(short8*)((char*)wfrag + byte) = v;
  } else if (lane < 32) {
    const int kgrp = lane >> 3, col = lane & 7;
    const int k = kh * 512 + ko * 32 + kgrp * 8;
    const int row = 2 * HDIM + j0 + col;
    const float* src = wsrc + (size_t)row * HDIM + k;
    short8 v;
#pragma unroll
    for (int e = 0; e < 8; ++e) v[e] = (short)f2bf(src[e]);
    const size_t byte = (size_t)bid * WBLK_BYTES + c2 * COMBO_BYTES + TL1_OFF + ko * 512 + lane * 16;
    *(short8*)((char*)wfrag + byte) = v;
  }
}

// ---------- dec/head weight frag pre-pack ----------
__global__ __launch_bounds__(256) void wprep2_kernel(
    const float* __restrict__ dec_w, const float* __restrict__ exp_w,
    const float* __restrict__ log_w,
    ushort_t* __restrict__ dwfrag, ushort_t* __restrict__ hwfrag)
{
  const int lane = threadIdx.x & 63;
  const int wv   = threadIdx.x >> 6;
  const int c    = blockIdx.x * 4 + wv;   // 0..2303
  short8 v;
  if (c < 2048) {
    const int nt = c >> 5, kc = c & 31;
    const int row = nt * 16 + (lane & 15);
    const int k   = kc * 32 + (lane >> 4) * 8;
    const float* src = dec_w + (size_t)row * HDIM + k;
#pragma unroll
    for (int e = 0; e < 8; ++e) v[e] = (short)f2bf(src[e]);
    *(short8*)(dwfrag + (size_t)c * 512 + lane * 8) = v;
  } else {
    const int c2 = c - 2048;
    const int nt = c2 >> 5, kc = c2 & 31;
    const int row = nt * 16 + (lane & 15);
    const int k   = kc * 32 + (lane >> 4) * 8;
    const float* src = (row < 64) ? (exp_w + (size_t)row * HDIM + k)
                                  : (log_w + (size_t)(row - 64) * HDIM + k);
#pragma unroll
    for (int e = 0; e < 8; ++e) v[e] = (short)f2bf(src[e]);
    *(short8*)(hwfrag + (size_t)c2 * 512 + lane * 8) = v;
  }
}

// ---------- persistent recurrent kernel ----------
// L0 = blocks 0..127 (producer into 32-deep h0 ring); L1 = blocks 128..255.
// Flattened flag barrier (no leader/release hops); deep-pipelined A prefetch.
__global__ __launch_bounds__(512, 1) void rnn_persist(
    const ushort_t* __restrict__ ench1,
    const ushort_t* __restrict__ wfrag,
    const float* __restrict__ b_ih, const float* __restrict__ b_hh,
    ushort_t* __restrict__ h0ring,        // 32 x [64][1024] bf16
    ushort_t* __restrict__ h1ring,        // 32 x [64][1024] bf16
    ushort_t* __restrict__ h1_all,        // == ench1 (slices for dechead)
    u32* __restrict__ l0_flags, u32* __restrict__ l1_flags)
{
  extern __shared__ char smem[];          // 96KB weights + 32KB exchange
  float* lds_part = (float*)(smem + WBLK_BYTES);

  const int tid  = threadIdx.x;
  const int lane = tid & 63;
  const int wid  = tid >> 6;
  const int bid  = blockIdx.x;
  const int layer = bid >> 7;
  const int j0    = (bid & 127) * 8;
  const int mp = wid & 1, g = (wid >> 1) & 1, kh = wid >> 2;
  const int col = lane & 15, kgrp = lane >> 4;
  const bool isL1 = (layer == 1);
  const int gbid = bid & 127;
  u32* ownf = isL1 ? l1_flags : l0_flags;

  // ---- one-time: stage 96KB weight image into LDS ----
  {
    const uint4* src = (const uint4*)((const char*)wfrag + (size_t)bid * WBLK_BYTES);
    uint4* dst = (uint4*)smem;
#pragma unroll 4
    for (int i = tid; i < WBLK_BYTES / 16; i += 512) dst[i] = src[i];
  }

  const int c2 = g * 2 + kh;
  const char* w0 = smem + c2 * COMBO_BYTES + lane * 16;
  const char* w1 = smem + c2 * COMBO_BYTES + TL1_OFF + (kgrp * 8 + (col & 7)) * 16;

  // ---- biases ----
  float bA = 0.f, bB = 0.f, bC = 0.f;
  {
    const float* bi = b_ih + layer * 3 * HDIM;
    const float* bh = b_hh + layer * 3 * HDIM;
    if (col < 8) {
      const int j = j0 + col;
      bA = bi[j] + bh[j];
      bB = bi[2 * HDIM + j];
      bC = bh[2 * HDIM + j];
    } else {
      const int j = j0 + col - 8;
      bA = bi[HDIM + j] + bh[HDIM + j];
    }
  }

  f32x4 hp = {0.f, 0.f, 0.f, 0.f};  // running fp32 h-state (waves 0-3, col<8)

  __syncthreads();  // LDS weight image ready

  for (int i = 0; i < T_STEPS; ++i) {
    // ---- P1: L1 waits for h0(i) ----
    if (isL1) {
      if (tid < 32) poll4(l0_flags, tid, (u32)(i + 1));
      __syncthreads();
    }

    const ushort_t* A1 = isL1 ? (h0ring + (size_t)(i & (RING_D - 1)) * BH)
                              : (ench1 + (size_t)i * BH);
    const ushort_t* A2 = isL1 ? (h1ring + (size_t)((i - 1) & (RING_D - 1)) * BH)
                              : (h0ring + (size_t)((i - 1) & (RING_D - 1)) * BH);
    const ushort_t* A = g ? A2 : A1;
    const ushort_t* Arow0 = A + (size_t)(mp * 32 + col) * HDIM + kh * 512 + kgrp * 8;
    const ushort_t* Arow1 = Arow0 + 16 * HDIM;

    // ---- A1 prefetch (g=0 waves): overlaps with own-group poll ----
    uint4 areg[32];
    if (g == 0) {
#pragma unroll
      for (int ko = 0; ko < 16; ++ko) {
        areg[2 * ko]     = ld_g128(Arow0 + ko * 32);
        areg[2 * ko + 1] = ld_g128(Arow1 + ko * 32);
      }
    }

    // ---- P2: own-group barrier (h[i-1] ready) + L0 ring guard ----
    if (tid < 32) {
      poll4(ownf, tid, (u32)i);
      if (!isL1 && i >= RING_D) poll4(l1_flags, tid, (u32)(i - RING_D + 1));
    }
    __syncthreads();

    // ---- A2 loads (g=1 waves) ----
    if (g == 1) {
#pragma unroll
      for (int ko = 0; ko < 16; ++ko) {
        areg[2 * ko]     = ld_g128(Arow0 + ko * 32);
        areg[2 * ko + 1] = ld_g128(Arow1 + ko * 32);
      }
    }

    // ---- MFMA, staged waits ----
    f32x4 acc00 = {0,0,0,0}, acc01 = {0,0,0,0}, acc10 = {0,0,0,0}, acc11 = {0,0,0,0};
    asm volatile("s_waitcnt vmcnt(16)" ::: "memory");
    __builtin_amdgcn_sched_barrier(0);
#pragma unroll
    for (int ko = 0; ko < 8; ++ko) {
      const short8 b0 = *(const short8*)(w0 + ko * 1024);
      const short8 b1 = *(const short8*)(w1 + ko * 512);
      U4S8 a0, a1; a0.u = areg[2 * ko]; a1.u = areg[2 * ko + 1];
      acc00 = __builtin_amdgcn_mfma_f32_16x16x32_bf16(a0.s, b0, acc00, 0, 0, 0);
      acc01 = __builtin_amdgcn_mfma_f32_16x16x32_bf16(a0.s, b1, acc01, 0, 0, 0);
      acc10 = __builtin_amdgcn_mfma_f32_16x16x32_bf16(a1.s, b0, acc10, 0, 0, 0);
      acc11 = __builtin_amdgcn_mfma_f32_16x16x32_bf16(a1.s, b1, acc11, 0, 0, 0);
    }
    asm volatile("s_waitcnt vmcnt(0)" ::: "memory");
    __builtin_amdgcn_sched_barrier(0);
#pragma unroll
    for (int ko = 8; ko < 16; ++ko) {
      const short8 b0 = *(const short8*)(w0 + ko * 1024);
      const short8 b1 = *(const short8*)(w1 + ko * 512);
      U4S8 a0, a1; a0.u = areg[2 * ko]; a1.u = areg[2 * ko + 1];
      acc00 = __builtin_amdgcn_mfma_f32_16x16x32_bf16(a0.s, b0, acc00, 0, 0, 0);
      acc01 = __builtin_amdgcn_mfma_f32_16x16x32_bf16(a0.s, b1, acc01, 0, 0, 0);
      acc10 = __builtin_amdgcn_mfma_f32_16x16x32_bf16(a1.s, b0, acc10, 0, 0, 0);
      acc11 = __builtin_amdgcn_mfma_f32_16x16x32_bf16(a1.s, b1, acc11, 0, 0, 0);
    }

    const int base = (wid * 4) * 256 + lane * 4;
    *(f32x4*)&lds_part[base      ] = acc00;
    *(f32x4*)&lds_part[base + 256] = acc01;
    *(f32x4*)&lds_part[base + 512] = acc10;
    *(f32x4*)&lds_part[base + 768] = acc11;

    __syncthreads();

    if (wid < 4) {
      const int m = wid, mpe = m >> 1, ime = m & 1;
      const int i00 = ((0 * 4 + 0 * 2 + mpe) * 4 + ime * 2);
      const int i01 = ((1 * 4 + 0 * 2 + mpe) * 4 + ime * 2);
      const int i10 = ((0 * 4 + 1 * 2 + mpe) * 4 + ime * 2);
      const int i11 = ((1 * 4 + 1 * 2 + mpe) * 4 + ime * 2);
      const int lo = lane * 4;
      f32x4 girz = *(f32x4*)&lds_part[i00 * 256 + lo] + *(f32x4*)&lds_part[i01 * 256 + lo];
      f32x4 gin  = *(f32x4*)&lds_part[(i00 + 1) * 256 + lo] + *(f32x4*)&lds_part[(i01 + 1) * 256 + lo];
      f32x4 ghrz = *(f32x4*)&lds_part[i10 * 256 + lo] + *(f32x4*)&lds_part[i11 * 256 + lo];
      f32x4 ghn  = *(f32x4*)&lds_part[(i10 + 1) * 256 + lo] + *(f32x4*)&lds_part[(i11 + 1) * 256 + lo];

      ushort_t* hdst = isL1 ? (h1ring + (size_t)(i & (RING_D - 1)) * BH)
                            : (h0ring + (size_t)(i & (RING_D - 1)) * BH);
      ushort_t* hall = isL1 ? (h1_all + (size_t)i * BH) : (ushort_t*)0;

#pragma unroll
      for (int e = 0; e < 4; ++e) {
        const float rz = sigm(girz[e] + ghrz[e] + bA);
        const float nv = tanhf(gin[e] + bB + rz * (ghn[e] + bC));
        const float zv = __shfl_xor(rz, 8);
        const int b = m * 16 + kgrp * 4 + e;
        float h = 0.f;
        if (col < 8) {
          h = (1.f - zv) * nv + zv * hp[e];
          hp[e] = h;
        }
        const u32 hb = f2bf_u(h);
        const u32 pb = (u32)__shfl_xor((int)hb, 1);
        if (col < 8 && (col & 1) == 0) {
          const u32 pack = hb | (pb << 16);
          st_sc32((u32*)(hdst + b * HDIM + j0 + col), pack);
          if (hall) st_sc32((u32*)(hall + b * HDIM + j0 + col), pack);
        }
      }
    }

    __syncthreads();  // drains all sc1 h-stores (vmcnt 0) before flag arrival
    if (tid == 0) st_sc32(ownf + gbid, (u32)(i + 1));
  }
}

// ---------- fused decoder + heads (bf16 MFMA) ----------
#define AST 1032
__global__ __launch_bounds__(512, 1) void dechead_kernel(
    const ushort_t* __restrict__ h1_all,
    const ushort_t* __restrict__ dwfrag, const ushort_t* __restrict__ hwfrag,
    const float* __restrict__ dec_b, const float* __restrict__ exp_b,
    const float* __restrict__ log_b, float* __restrict__ out)
{
  extern __shared__ char smem2[];
  ushort_t* Alds = (ushort_t*)smem2;             // [32][AST]
  ushort_t* Rlds = Alds + 32 * AST;              // [32][AST]

  const int tid  = threadIdx.x;
  const int lane = tid & 63;
  const int wv   = tid >> 6;
  const int base = blockIdx.x * 32;

  {
    const uint4* src = (const uint4*)(h1_all + (size_t)base * HDIM);
#pragma unroll
    for (int ii = 0; ii < 8; ++ii) {
      const int idx = ii * 512 + tid;
      const int row = idx >> 7;
      const int k   = (idx & 127) * 8;
      *(uint4*)(Alds + row * AST + k) = src[idx];
    }
  }
  __syncthreads();

  f32x4 acc[8][2];
#pragma unroll
  for (int t = 0; t < 8; ++t) { acc[t][0] = (f32x4){0,0,0,0}; acc[t][1] = (f32x4){0,0,0,0}; }

  const int r0 = lane & 15, kg = lane >> 4;
  const int nt0 = wv * 8;
#pragma unroll 1
  for (int t = 0; t < 8; ++t) {
    const ushort_t* bsrc = dwfrag + (size_t)(nt0 + t) * 32 * 512 + lane * 8;
    f32x4 c0 = acc[t][0], c1 = acc[t][1];
#pragma unroll
    for (int kc = 0; kc < 32; ++kc) {
      const short8 b  = *(const short8*)(bsrc + kc * 512);
      const short8 a0 = *(const short8*)(Alds + r0 * AST + kc * 32 + kg * 8);
      const short8 a1 = *(const short8*)(Alds + (16 + r0) * AST + kc * 32 + kg * 8);
      c0 = __builtin_amdgcn_mfma_f32_16x16x32_bf16(a0, b, c0, 0, 0, 0);
      c1 = __builtin_amdgcn_mfma_f32_16x16x32_bf16(a1, b, c1, 0, 0, 0);
    }
    acc[t][0] = c0; acc[t][1] = c1;
  }

#pragma unroll
  for (int t = 0; t < 8; ++t) {
    const int colc = (nt0 + t) * 16 + r0;
    const float db = dec_b[colc];
#pragma unroll
    for (int m = 0; m < 2; ++m) {
      const f32x4 v = acc[t][m];
#pragma unroll
      for (int e = 0; e < 4; ++e) {
        const int row = m * 16 + kg * 4 + e;
        Rlds[row * AST + colc] = (ushort_t)f2bf_u(tanhf(v[e] + db));
      }
    }
  }
  __syncthreads();

  f32x4 h0a = {0,0,0,0}, h1a = {0,0,0,0};
  {
    const ushort_t* bsrc = hwfrag + (size_t)wv * 32 * 512 + lane * 8;
#pragma unroll
    for (int kc = 0; kc < 32; ++kc) {
      const short8 b  = *(const short8*)(bsrc + kc * 512);
      const short8 a0 = *(const short8*)(Rlds + r0 * AST + kc * 32 + kg * 8);
      const short8 a1 = *(const short8*)(Rlds + (16 + r0) * AST + kc * 32 + kg * 8);
      h0a = __builtin_amdgcn_mfma_f32_16x16x32_bf16(a0, b, h0a, 0, 0, 0);
      h1a = __builtin_amdgcn_mfma_f32_16x16x32_bf16(a1, b, h1a, 0, 0, 0);
    }
  }
  const int y = wv * 16 + r0;
  if (wv < 4) {
    const float eb = exp_b[y];
#pragma unroll
    for (int m = 0; m < 2; ++m) {
      const f32x4 v = (m == 0) ? h0a : h1a;
#pragma unroll
      for (int e = 0; e < 4; ++e) {
        const int row = m * 16 + kg * 4 + e;
        out[(size_t)(base + row) * YDIM + y] = v[e] + eb;
      }
    }
  } else {
    const int yv = y - 64;
    const float lb = log_b[yv];
#pragma unroll
    for (int m = 0; m < 2; ++m) {
      const f32x4 v = (m == 0) ? h0a : h1a;
#pragma unroll
      for (int e = 0; e < 4; ++e) {
        const int row = m * 16 + kg * 4 + e;
        out[(size_t)(T_STEPS * BATCH * YDIM) + (size_t)(base + row) * YDIM + yv] = expf(v[e] + lb);
      }
    }
  }
}

// ---------- host ----------
extern "C" void kernel_launch(void* const* d_in, const int* in_sizes, int n_in,
                              void* d_out, int out_size, void* d_ws, size_t ws_size,
                              hipStream_t stream) {
  (void)in_sizes; (void)n_in; (void)out_size; (void)ws_size;
  const float* x     = (const float*)d_in[0];
  const float* enc_w = (const float*)d_in[1];
  const float* enc_b = (const float*)d_in[2];
  const float* w_ih  = (const float*)d_in[3];
  const float* w_hh  = (const float*)d_in[4];
  const float* b_ih  = (const float*)d_in[5];
  const float* b_hh  = (const float*)d_in[6];
  const float* dec_w = (const float*)d_in[7];
  const float* dec_b = (const float*)d_in[8];
  const float* exp_w = (const float*)d_in[9];
  const float* exp_b = (const float*)d_in[10];
  const float* log_w = (const float*)d_in[11];
  const float* log_b = (const float*)d_in[12];
  float* out = (float*)d_out;

  char* ws = (char*)d_ws;
  u32*      l0f     = (u32*)ws;                             // 128 u32 (contiguous)
  u32*      l1f     = (u32*)(ws + 4096);                    // 128 u32
  ushort_t* wfrag   = (ushort_t*)(ws + 2097152);            // 24 MB
  ushort_t* h0ring  = (ushort_t*)(ws + 27262976);           // 4 MB (32 slots)
  ushort_t* h1ring  = (ushort_t*)(ws + 31457280);           // 4 MB
  ushort_t* ench1   = (ushort_t*)(ws + 35651584);           // 64 MB enc slices / h1_all
  ushort_t* dwfrag  = (ushort_t*)(ws + 102760448);          // 2 MB
  ushort_t* hwfrag  = (ushort_t*)(ws + 104857600);          // 256 KB

  hipMemsetAsync(ws, 0, 8192, stream);                      // flag arrays
  hipMemsetAsync(ws + 27262976, 0, 8388608, stream);        // both rings

  enc_kernel<<<32768, 256, 0, stream>>>(x, enc_w, enc_b, ench1);
  wprep_kernel<<<8192, 256, 0, stream>>>(w_ih, w_hh, wfrag);
  wprep2_kernel<<<576, 256, 0, stream>>>(dec_w, exp_w, log_w, dwfrag, hwfrag);

  {
    static int lds_opted = 0;
    if (!lds_opted) {
      hipFuncSetAttribute((const void*)rnn_persist,
                          hipFuncAttributeMaxDynamicSharedMemorySize, 131072);
      hipFuncSetAttribute((const void*)dechead_kernel,
                          hipFuncAttributeMaxDynamicSharedMemorySize, 2 * 32 * AST * 2);
      lds_opted = 1;
    }
    void* args[9];
    args[0] = (void*)&ench1;
    args[1] = (void*)&wfrag;
    args[2] = (void*)&b_ih;
    args[3] = (void*)&b_hh;
    args[4] = (void*)&h0ring;
    args[5] = (void*)&h1ring;
    args[6] = (void*)&ench1;
    args[7] = (void*)&l0f;
    args[8] = (void*)&l1f;
    hipLaunchCooperativeKernel((const void*)rnn_persist, dim3(256), dim3(512),
                               args, 131072, stream);
  }

  dechead_kernel<<<1024, 512, 2 * 32 * AST * 2, stream>>>(
      ench1, dwfrag, hwfrag, dec_b, exp_b, log_b, out);
}